// Round 1
// baseline (22677.335 us; speedup 1.0000x reference)
//
#include <hip/hip_runtime.h>
#include <cstddef>

#define S_LEN 128
#define B_SZ  64
#define E_SZ  1024
#define NLBL  5
#define KB    64
#define KBP   68

// ws layout (floats):
//   h0: [2 dirs][2 bufs][B][E]   offset 0       size 262144
//   h1: [2][2][B][E]             offset 262144  size 262144
//   c0: [2][B][E]                offset 524288  size 131072
//   c1: [2][B][E]                offset 655360  size 131072
//   w : [B][S]                   offset 786432  size 8192
#define OFF_H0 0
#define OFF_H1 262144
#define OFF_C0 524288
#define OFF_C1 655360
#define OFF_W  786432
#define WS_TOTAL 794624

struct Params {
  const float* x;          // inputs [B,S,E]
  const float* W[2][3];    // [dir][gate f,i,c] -> [L,2E,E]
  const float* bias[2][3]; // [L,E]
  const float* wordW;      // [2E]
  float* h0;
  float* h1;
  float* c0;
  float* c1;
  float* w;
};

__global__ __launch_bounds__(256)
void init_kernel(float* ws, const float* hs, const float* cs, const float* wordb) {
  size_t i = (size_t)blockIdx.x * 256 + threadIdx.x;
  if (i < OFF_C0) {
    // h0 and h1 regions: broadcast initial hidden state to all dirs/bufs
    size_t be = i & (size_t)(B_SZ * E_SZ - 1);
    ws[i] = hs[be];
  } else if (i < OFF_W) {
    size_t be = (i - OFF_C0) & (size_t)(B_SZ * E_SZ - 1);
    ws[i] = cs[be];
  } else if (i < WS_TOTAL) {
    ws[i] = wordb[0];
  }
}

template<int LAYER>
__global__ __launch_bounds__(256)
void step_kernel(Params p, int t) {
  __shared__ float zs[32][KBP];
  __shared__ float wsT[3 * 16 * KBP];
  __shared__ float red[32][17];

  const int tid = threadIdx.x;
  const int blk = blockIdx.x;
  const int ct = blk & 63;          // 64 col tiles of 16
  const int rt = (blk >> 6) & 1;    // 2 row tiles of 32
  const int d  = blk >> 7;          // direction
  const int td = d ? (S_LEN - 1 - t) : t;
  const int cur = t & 1, nxt = cur ^ 1;

  const int tx = tid & 15;          // col in tile
  const int ty = tid >> 4;          // 0..15; rows ty, ty+16
  const int j  = ct * 16 + tx;      // global output column

  const float* hsrc  = (LAYER == 0 ? p.h0 : p.h1) + (size_t)(d * 2 + cur) * (B_SZ * E_SZ);
  const float* h0new = p.h0 + (size_t)(d * 2 + nxt) * (B_SZ * E_SZ);
  const float* W0 = p.W[d][0] + (size_t)LAYER * 2 * E_SZ * E_SZ;
  const float* W1 = p.W[d][1] + (size_t)LAYER * 2 * E_SZ * E_SZ;
  const float* W2 = p.W[d][2] + (size_t)LAYER * 2 * E_SZ * E_SZ;

  float acc[3][2] = {{0.f, 0.f}, {0.f, 0.f}, {0.f, 0.f}};

  const int lr  = tid >> 3;         // 0..31 row for z staging
  const int lk0 = (tid & 7) * 8;    // 0..56
  const int gb  = rt * 32 + lr;     // global row b

  for (int k0 = 0; k0 < 2 * E_SZ; k0 += KB) {
    // stage z chunk [32 rows][64 k] (branch is uniform per chunk: 1024 % 64 == 0)
    {
      const int kk = k0 + lk0;
      const float* src;
      size_t base;
      if (kk < E_SZ) { src = hsrc; base = (size_t)gb * E_SZ + kk; }
      else if (LAYER == 0) { src = p.x; base = ((size_t)gb * S_LEN + td) * E_SZ + (kk - E_SZ); }
      else { src = h0new; base = (size_t)gb * E_SZ + (kk - E_SZ); }
      float4 v0 = *(const float4*)(src + base);
      float4 v1 = *(const float4*)(src + base + 4);
      *(float4*)&zs[lr][lk0]     = v0;
      *(float4*)&zs[lr][lk0 + 4] = v1;
    }
    // stage W chunk transposed: wsT[(g*16+tx)*KBP + kk]
    #pragma unroll
    for (int i = 0; i < 12; ++i) {
      const int kg  = ty + i * 16;  // 0..191 = 3 gates * 64 kk
      const int g   = kg >> 6;
      const int kkl = kg & 63;
      const float* Wg = (g == 0 ? W0 : (g == 1 ? W1 : W2));
      wsT[(g * 16 + tx) * KBP + kkl] = Wg[(size_t)(k0 + kkl) * E_SZ + j];
    }
    __syncthreads();
    #pragma unroll
    for (int kk = 0; kk < KB; kk += 4) {
      const float4 z0 = *(const float4*)&zs[ty][kk];
      const float4 z1 = *(const float4*)&zs[ty + 16][kk];
      const float4 wf = *(const float4*)&wsT[(0 * 16 + tx) * KBP + kk];
      const float4 wi = *(const float4*)&wsT[(1 * 16 + tx) * KBP + kk];
      const float4 wc = *(const float4*)&wsT[(2 * 16 + tx) * KBP + kk];
      acc[0][0] += z0.x * wf.x + z0.y * wf.y + z0.z * wf.z + z0.w * wf.w;
      acc[0][1] += z1.x * wf.x + z1.y * wf.y + z1.z * wf.z + z1.w * wf.w;
      acc[1][0] += z0.x * wi.x + z0.y * wi.y + z0.z * wi.z + z0.w * wi.w;
      acc[1][1] += z1.x * wi.x + z1.y * wi.y + z1.z * wi.z + z1.w * wi.w;
      acc[2][0] += z0.x * wc.x + z0.y * wc.y + z0.z * wc.z + z0.w * wc.w;
      acc[2][1] += z1.x * wc.x + z1.y * wc.y + z1.z * wc.z + z1.w * wc.w;
    }
    __syncthreads();
  }

  const float bfv = p.bias[d][0][LAYER * E_SZ + j];
  const float biv = p.bias[d][1][LAYER * E_SZ + j];
  const float bcv = p.bias[d][2][LAYER * E_SZ + j];
  float* cst  = (LAYER == 0 ? p.c0 : p.c1) + (size_t)d * (B_SZ * E_SZ);
  float* hdst = (LAYER == 0 ? p.h0 : p.h1) + (size_t)(d * 2 + nxt) * (B_SZ * E_SZ);

  float wcontrib[2];
  #pragma unroll
  for (int r = 0; r < 2; ++r) {
    const int b = rt * 32 + ty + r * 16;
    const float af = acc[0][r] + bfv;
    const float ai = acc[1][r] + biv;
    const float ac = acc[2][r] + bcv;
    const float fg = 1.f / (1.f + expf(-af));
    const float ig = 1.f / (1.f + expf(-ai));
    const float gg = tanhf(ac);
    const float c_old = cst[(size_t)b * E_SZ + j];
    const float c_new = c_old * fg + ig * gg;
    const float h_new = tanhf(c_new) * fg;   // forget gate reused as output gate
    cst[(size_t)b * E_SZ + j]  = c_new;
    hdst[(size_t)b * E_SZ + j] = h_new;
    wcontrib[r] = h_new * p.wordW[d * E_SZ + j];
  }

  if (LAYER == 1) {
    red[ty][tx]      = wcontrib[0];
    red[ty + 16][tx] = wcontrib[1];
    __syncthreads();
    if (tid < 32) {
      float s = 0.f;
      #pragma unroll
      for (int q = 0; q < 16; ++q) s += red[tid][q];
      atomicAdd(&p.w[(size_t)(rt * 32 + tid) * S_LEN + td], s);
    }
  }
}

__global__ __launch_bounds__(320)
void final_kernel(const float* w, const float* predW, const float* predb, float* out) {
  const int tid = threadIdx.x;
  if (tid >= B_SZ * NLBL) return;
  const int b = tid / NLBL, lab = tid % NLBL;
  float s = predb[lab];
  #pragma unroll 8
  for (int t = 0; t < S_LEN; ++t) s += w[b * S_LEN + t] * predW[t * NLBL + lab];
  out[tid] = s;
}

extern "C" void kernel_launch(void* const* d_in, const int* in_sizes, int n_in,
                              void* d_out, int out_size, void* d_ws, size_t ws_size,
                              hipStream_t stream) {
  float* ws = (float*)d_ws;
  Params p;
  p.x = (const float*)d_in[0];
  p.W[0][0] = (const float*)d_in[5];  p.bias[0][0] = (const float*)d_in[6];
  p.W[0][1] = (const float*)d_in[7];  p.bias[0][1] = (const float*)d_in[8];
  p.W[0][2] = (const float*)d_in[9];  p.bias[0][2] = (const float*)d_in[10];
  p.W[1][0] = (const float*)d_in[11]; p.bias[1][0] = (const float*)d_in[12];
  p.W[1][1] = (const float*)d_in[13]; p.bias[1][1] = (const float*)d_in[14];
  p.W[1][2] = (const float*)d_in[15]; p.bias[1][2] = (const float*)d_in[16];
  p.wordW = (const float*)d_in[17];
  p.h0 = ws + OFF_H0;
  p.h1 = ws + OFF_H1;
  p.c0 = ws + OFF_C0;
  p.c1 = ws + OFF_C1;
  p.w  = ws + OFF_W;

  init_kernel<<<WS_TOTAL / 256, 256, 0, stream>>>(
      ws, (const float*)d_in[2], (const float*)d_in[1], (const float*)d_in[18]);

  for (int t = 0; t < S_LEN; ++t) {
    step_kernel<0><<<256, 256, 0, stream>>>(p, t);
    step_kernel<1><<<256, 256, 0, stream>>>(p, t);
  }

  final_kernel<<<1, 320, 0, stream>>>(p.w, (const float*)d_in[19],
                                      (const float*)d_in[20], (float*)d_out);
}

// Round 2
// 11439.820 us; speedup vs baseline: 1.9823x; 1.9823x over previous
//
#include <hip/hip_runtime.h>
#include <cstddef>

typedef _Float16 half8 __attribute__((ext_vector_type(8)));
typedef float f32x4 __attribute__((ext_vector_type(4)));

#define S_LEN 128
#define B_SZ  64
#define E_SZ  1024
#define NLBL  5
#define KC    128
#define NC    16
#define BKP   136

// ws layout (floats)
#define OFF_H0 0
#define OFF_H1 262144
#define OFF_C0 524288
#define OFF_C1 655360
#define OFF_W  786432
#define WS_TOTAL 794624

struct Params {
  const float* x;          // inputs [B,S,E]
  const float* W[2][3];    // [dir][gate f,i,c] -> [L,2E,E]
  const float* bias[2][3]; // [L,E]
  const float* wordW;      // [2E]
  float* h0;
  float* h1;
  float* c0;
  float* c1;
  float* w;
};

__global__ __launch_bounds__(256)
void init_kernel(float* ws, const float* hs, const float* cs, const float* wordb) {
  size_t i = (size_t)blockIdx.x * 256 + threadIdx.x;
  if (i < OFF_C0) {
    size_t be = i & (size_t)(B_SZ * E_SZ - 1);
    ws[i] = hs[be];
  } else if (i < OFF_W) {
    size_t be = (i - OFF_C0) & (size_t)(B_SZ * E_SZ - 1);
    ws[i] = cs[be];
  } else if (i < WS_TOTAL) {
    ws[i] = wordb[0];
  }
}

// Per (step, layer): C[d][64][3*1024] = z[d] @ [Wf|Wi|Wc], f16 MFMA with
// 2-term split on A (z), single f16 on B (weights). Block = (dir, 16-col
// group): all 3 gates, full M=64, K=2048. 8 waves = (mhalf 2) x (kquarter 4).
template<int LAYER>
__global__ __launch_bounds__(512)
void step_kernel(Params p, int t) {
  __shared__ __align__(16) unsigned char lds_raw[53248];
  _Float16* BtBase = (_Float16*)lds_raw;            // 2 x [48][BKP] f16 = 26112 B
  float* pre = (float*)lds_raw;                     // [4][3][64][16] f32 = 49152 B (after K loop)
  float* wcs = (float*)(lds_raw + 49152);           // [64][16] f32 = 4096 B

  const int tid = threadIdx.x;
  const int l   = tid & 63;
  const int lr  = l & 15;
  const int lg  = l >> 4;
  const int wv  = tid >> 6;
  const int kq  = wv & 3;   // k-quarter within chunk
  const int mg  = wv >> 2;  // m-half (rows mg*32..mg*32+31)

  const int blk = blockIdx.x;
  const int jg  = blk & 63;
  const int d   = blk >> 6;
  const int j0  = jg * 16;
  const int td  = d ? (S_LEN - 1 - t) : t;
  const int cur = t & 1, nxt = cur ^ 1;

  const float* hsrc = (LAYER == 0 ? p.h0 : p.h1) + (size_t)(d * 2 + cur) * (B_SZ * E_SZ);
  const float* isrc = (LAYER == 0) ? p.x
                                   : p.h0 + (size_t)(d * 2 + nxt) * (B_SZ * E_SZ);
  const float* Wg0 = p.W[d][0] + (size_t)LAYER * 2 * E_SZ * E_SZ;
  const float* Wg1 = p.W[d][1] + (size_t)LAYER * 2 * E_SZ * E_SZ;
  const float* Wg2 = p.W[d][2] + (size_t)LAYER * 2 * E_SZ * E_SZ;

  // ---- helpers ----
  auto loadA = [&](int c, float4 dst[2][2]) {
    const int kk = c * KC + kq * 32 + lg * 8;
    #pragma unroll
    for (int mi = 0; mi < 2; ++mi) {
      const int row = (mg * 2 + mi) * 16 + lr;
      const float* ptr;
      if (kk < E_SZ) {
        ptr = hsrc + (size_t)row * E_SZ + kk;
      } else if (LAYER == 0) {
        ptr = isrc + ((size_t)row * S_LEN + td) * E_SZ + (kk - E_SZ);
      } else {
        ptr = isrc + (size_t)row * E_SZ + (kk - E_SZ);
      }
      dst[mi][0] = *(const float4*)ptr;
      dst[mi][1] = *(const float4*)(ptr + 4);
    }
  };
  auto loadB = [&](int c, float4 breg[3]) {
    #pragma unroll
    for (int it = 0; it < 3; ++it) {
      const int idx = tid + it * 512;
      const int row = idx >> 2;            // 0..383 = 3 gates x 128 k
      const int g   = row >> 7;
      const int kk  = row & 127;
      const int q   = idx & 3;
      const float* W = (g == 0 ? Wg0 : (g == 1 ? Wg1 : Wg2));
      breg[it] = *(const float4*)(W + (size_t)(c * KC + kk) * E_SZ + j0 + q * 4);
    }
  };
  auto writeB = [&](const float4 breg[3], int buf) {
    _Float16* Bt = BtBase + buf * (48 * BKP);
    #pragma unroll
    for (int it = 0; it < 3; ++it) {
      const int idx = tid + it * 512;
      const int row = idx >> 2;
      const int g   = row >> 7;
      const int kk  = row & 127;
      const int q   = idx & 3;
      #pragma unroll
      for (int jj = 0; jj < 4; ++jj)
        Bt[(g * 16 + q * 4 + jj) * BKP + kk] = (_Float16)breg[it][jj];
    }
  };

  // ---- prologue ----
  float4 aCur[2][2], aNxt[2][2];
  float4 breg[3];
  loadB(0, breg);
  loadA(0, aCur);
  writeB(breg, 0);
  __syncthreads();

  const f32x4 zero = {0.f, 0.f, 0.f, 0.f};
  f32x4 acc[3][2];
  #pragma unroll
  for (int g = 0; g < 3; ++g) { acc[g][0] = zero; acc[g][1] = zero; }

  // ---- main K loop: 16 chunks of 128, double-buffered B, 1 barrier/chunk ----
  #pragma unroll
  for (int c = 0; c < NC; ++c) {
    half8 a1[2], a2[2];
    #pragma unroll
    for (int mi = 0; mi < 2; ++mi) {
      #pragma unroll
      for (int i = 0; i < 8; ++i) {
        const float v = (i < 4) ? aCur[mi][0][i] : aCur[mi][1][i - 4];
        const _Float16 h = (_Float16)v;
        a1[mi][i] = h;
        a2[mi][i] = (_Float16)(v - (float)h);
      }
    }
    if (c + 1 < NC) { loadB(c + 1, breg); loadA(c + 1, aNxt); }

    const _Float16* BtR = BtBase + (c & 1) * (48 * BKP) + kq * 32 + lg * 8;
    half8 bf[3];
    #pragma unroll
    for (int g = 0; g < 3; ++g)
      bf[g] = *(const half8*)(BtR + (g * 16 + lr) * BKP);

    #pragma unroll
    for (int g = 0; g < 3; ++g) {
      acc[g][0] = __builtin_amdgcn_mfma_f32_16x16x32_f16(a1[0], bf[g], acc[g][0], 0, 0, 0);
      acc[g][1] = __builtin_amdgcn_mfma_f32_16x16x32_f16(a1[1], bf[g], acc[g][1], 0, 0, 0);
    }
    #pragma unroll
    for (int g = 0; g < 3; ++g) {
      acc[g][0] = __builtin_amdgcn_mfma_f32_16x16x32_f16(a2[0], bf[g], acc[g][0], 0, 0, 0);
      acc[g][1] = __builtin_amdgcn_mfma_f32_16x16x32_f16(a2[1], bf[g], acc[g][1], 0, 0, 0);
    }

    if (c + 1 < NC) {
      writeB(breg, (c + 1) & 1);
      __syncthreads();
      #pragma unroll
      for (int mi = 0; mi < 2; ++mi) {
        aCur[mi][0] = aNxt[mi][0];
        aCur[mi][1] = aNxt[mi][1];
      }
    }
  }

  // ---- reduce k-quarter partials via LDS ----
  __syncthreads();   // Bt buffers dead; reuse as pre[]
  #pragma unroll
  for (int g = 0; g < 3; ++g)
    #pragma unroll
    for (int mi = 0; mi < 2; ++mi)
      #pragma unroll
      for (int pp = 0; pp < 4; ++pp)
        pre[(((kq * 3 + g) * 64) + (mg * 2 + mi) * 16 + lg * 4 + pp) * 16 + lr] =
            acc[g][mi][pp];
  __syncthreads();

  // ---- fused pointwise LSTM update + word projection ----
  float* cst  = (LAYER == 0 ? p.c0 : p.c1) + (size_t)d * (B_SZ * E_SZ);
  float* hdst = (LAYER == 0 ? p.h0 : p.h1) + (size_t)(d * 2 + nxt) * (B_SZ * E_SZ);

  #pragma unroll
  for (int rep = 0; rep < 2; ++rep) {
    const int e = tid + rep * 512;
    const int r = e >> 4;
    const int j = e & 15;
    const int jglob = j0 + j;
    float fp = p.bias[d][0][LAYER * E_SZ + jglob];
    float ip = p.bias[d][1][LAYER * E_SZ + jglob];
    float cp = p.bias[d][2][LAYER * E_SZ + jglob];
    #pragma unroll
    for (int k = 0; k < 4; ++k) {
      fp += pre[((k * 3 + 0) * 64 + r) * 16 + j];
      ip += pre[((k * 3 + 1) * 64 + r) * 16 + j];
      cp += pre[((k * 3 + 2) * 64 + r) * 16 + j];
    }
    const float fg = 1.f / (1.f + expf(-fp));
    const float ig = 1.f / (1.f + expf(-ip));
    const float gg = tanhf(cp);
    const float cold = cst[(size_t)r * E_SZ + jglob];
    const float cnew = cold * fg + ig * gg;
    const float hnew = tanhf(cnew) * fg;   // forget gate reused as output gate
    cst[(size_t)r * E_SZ + jglob]  = cnew;
    hdst[(size_t)r * E_SZ + jglob] = hnew;
    if (LAYER == 1) wcs[r * 16 + j] = hnew * p.wordW[(size_t)d * E_SZ + jglob];
  }

  if (LAYER == 1) {
    __syncthreads();
    if (tid < 64) {
      float s = 0.f;
      #pragma unroll
      for (int q = 0; q < 16; ++q) s += wcs[tid * 16 + q];
      atomicAdd(&p.w[(size_t)tid * S_LEN + td], s);
    }
  }
}

__global__ __launch_bounds__(320)
void final_kernel(const float* w, const float* predW, const float* predb, float* out) {
  const int tid = threadIdx.x;
  if (tid >= B_SZ * NLBL) return;
  const int b = tid / NLBL, lab = tid % NLBL;
  float s = predb[lab];
  #pragma unroll 8
  for (int t = 0; t < S_LEN; ++t) s += w[b * S_LEN + t] * predW[t * NLBL + lab];
  out[tid] = s;
}

extern "C" void kernel_launch(void* const* d_in, const int* in_sizes, int n_in,
                              void* d_out, int out_size, void* d_ws, size_t ws_size,
                              hipStream_t stream) {
  float* ws = (float*)d_ws;
  Params p;
  p.x = (const float*)d_in[0];
  p.W[0][0] = (const float*)d_in[5];  p.bias[0][0] = (const float*)d_in[6];
  p.W[0][1] = (const float*)d_in[7];  p.bias[0][1] = (const float*)d_in[8];
  p.W[0][2] = (const float*)d_in[9];  p.bias[0][2] = (const float*)d_in[10];
  p.W[1][0] = (const float*)d_in[11]; p.bias[1][0] = (const float*)d_in[12];
  p.W[1][1] = (const float*)d_in[13]; p.bias[1][1] = (const float*)d_in[14];
  p.W[1][2] = (const float*)d_in[15]; p.bias[1][2] = (const float*)d_in[16];
  p.wordW = (const float*)d_in[17];
  p.h0 = ws + OFF_H0;
  p.h1 = ws + OFF_H1;
  p.c0 = ws + OFF_C0;
  p.c1 = ws + OFF_C1;
  p.w  = ws + OFF_W;

  init_kernel<<<WS_TOTAL / 256, 256, 0, stream>>>(
      ws, (const float*)d_in[2], (const float*)d_in[1], (const float*)d_in[18]);

  for (int t = 0; t < S_LEN; ++t) {
    step_kernel<0><<<128, 512, 0, stream>>>(p, t);
    step_kernel<1><<<128, 512, 0, stream>>>(p, t);
  }

  final_kernel<<<1, 320, 0, stream>>>(p.w, (const float*)d_in[19],
                                      (const float*)d_in[20], (float*)d_out);
}

// Round 4
// 8076.962 us; speedup vs baseline: 2.8077x; 1.4164x over previous
//
#include <hip/hip_runtime.h>
#include <cstddef>
#include <cstdint>

typedef _Float16 half8 __attribute__((ext_vector_type(8)));
typedef float f32x4 __attribute__((ext_vector_type(4)));

#define S_LEN 128
#define B_SZ  64
#define E_SZ  1024
#define NLBL  5
#define NPHASE 129

// ---------------- new-path ws layout (bytes) ----------------
#define WOFF_WREC 0ull
#define WOFF_WINP 25165824ull
#define WOFF_X16  50331648ull
#define WOFF_H0   67108864ull
#define WOFF_H1   68157440ull
#define WOFF_C    69206016ull
#define WOFF_W    70254592ull
#define WOFF_BAR  70287360ull
#define WS_NEED   70287616ull

// init element count: h0 262144 + h1 262144 + c 262144 + w 8192 + bar 4
#define INIT_TOTAL 794628

struct PP {
  const float* x;
  const float* W[2][3];
  const float* bias[2][3];
  const float* wordW;
  _Float16* wrec;   // [ (d*2+l)*64 + j16 ][ g*16384 + (kc*64+lane)*8 + e ] f16
  _Float16* winp;
  _Float16* x16;    // [B][S][E] f16
  uint32_t* h0;     // [2d][2par][64][1024] packed (hi f16 low, lo f16 high)
  uint32_t* h1;
  float* c;         // [2d][2l][64][1024]
  float* w;         // [64][128]
  int* bar_cnt;     // [2]
  int* bar_flag;    // [2]
};

__device__ __forceinline__ uint32_t pack_split(float v) {
  _Float16 h = (_Float16)v;
  _Float16 l2 = (_Float16)(v - (float)h);
  return (uint32_t)__builtin_bit_cast(unsigned short, h) |
         ((uint32_t)__builtin_bit_cast(unsigned short, l2) << 16);
}

__device__ __forceinline__ void unpack8(uint4 a, uint4 b, half8& hi, half8& lo) {
  uint32_t v[8] = {a.x, a.y, a.z, a.w, b.x, b.y, b.z, b.w};
  #pragma unroll
  for (int i = 0; i < 8; ++i) {
    hi[i] = __builtin_bit_cast(_Float16, (unsigned short)(v[i] & 0xffffu));
    lo[i] = __builtin_bit_cast(_Float16, (unsigned short)(v[i] >> 16));
  }
}

// -------- conversion kernels (run every launch; deterministic) --------
__global__ __launch_bounds__(256)
void conv_w_kernel(PP p) {
  const int blk = blockIdx.x;           // (((d*2+l)*3+g)*64 + j16)*2 + part
  const int part = blk & 1;
  const int j16 = (blk >> 1) & 63;
  const int rest = blk >> 7;
  const int g = rest % 3;
  const int dl = rest / 3;
  const int l = dl & 1, d = dl >> 1;
  const int tid = threadIdx.x;
  const int l2 = tid & 63, kc0 = tid >> 6;
  const float* W = p.W[d][g] + (size_t)l * 2048 * 1024 + (size_t)(part ? 1024 : 0) * 1024;
  _Float16* out = (part ? p.winp : p.wrec) + (size_t)(dl * 64 + j16) * 49152 + (size_t)g * 16384;
  const int j = j16 * 16 + (l2 & 15);
  const int kbase = (l2 >> 4) * 8;
  #pragma unroll
  for (int ki = 0; ki < 8; ++ki) {
    const int kc = kc0 * 8 + ki;
    const int k0 = kc * 32 + kbase;
    half8 h;
    #pragma unroll
    for (int e2 = 0; e2 < 8; ++e2) h[e2] = (_Float16)W[(size_t)(k0 + e2) * 1024 + j];
    *(half8*)(out + ((size_t)kc * 64 + l2) * 8) = h;
  }
}

__global__ __launch_bounds__(256)
void conv_x_kernel(const float* x, _Float16* x16) {
  const size_t i8 = ((size_t)blockIdx.x * 256 + threadIdx.x) * 8;
  float4 a = *(const float4*)(x + i8);
  float4 b = *(const float4*)(x + i8 + 4);
  half8 h;
  h[0] = (_Float16)a.x; h[1] = (_Float16)a.y; h[2] = (_Float16)a.z; h[3] = (_Float16)a.w;
  h[4] = (_Float16)b.x; h[5] = (_Float16)b.y; h[6] = (_Float16)b.z; h[7] = (_Float16)b.w;
  *(half8*)(x16 + i8) = h;
}

__global__ __launch_bounds__(256)
void init2_kernel(PP p, const float* hs, const float* cs, const float* wordb) {
  const size_t i = (size_t)blockIdx.x * 256 + threadIdx.x;
  if (i < 262144) {
    p.h0[i] = pack_split(hs[i & 65535]);
  } else if (i < 524288) {
    p.h1[i - 262144] = pack_split(hs[i & 65535]);
  } else if (i < 786432) {
    p.c[i - 524288] = cs[i & 65535];
  } else if (i < 794624) {
    p.w[i - 786432] = wordb[0];
  } else if (i < INIT_TOTAL) {
    const int k = (int)(i - 794624);
    if (k < 2) p.bar_cnt[k] = 0; else p.bar_flag[k - 2] = 0;
  }
}

// ---------------- persistent bidirectional LSTM ----------------
__global__ __launch_bounds__(512, 1)
void lstm_persist(PP p) {
  extern __shared__ char smem[];
  _Float16* wlds = (_Float16*)smem;            // 98304 B: rec weights
  float* pre  = (float*)(smem + 98304);        // 49152 B: kq partials
  float* wred = (float*)(smem + 147456);       // 4096 B: word-proj scratch

  const int tid = threadIdx.x;
  const int l64 = tid & 63, lr = l64 & 15, lg = l64 >> 4;
  const int wv = tid >> 6, kq = wv & 3, mg = wv >> 2;
  const int blk = blockIdx.x;
  const int j16 = blk & 63, l = (blk >> 6) & 1, d = blk >> 7;
  const int j0 = j16 * 16;

  const size_t tileoff = (size_t)((d * 2 + l) * 64 + j16) * 49152;
  {
    const float4* src = (const float4*)(p.wrec + tileoff);
    float4* dst = (float4*)wlds;
    #pragma unroll
    for (int i = 0; i < 12; ++i) dst[tid + i * 512] = src[tid + i * 512];
  }
  const _Float16* wtile = p.winp + tileoff;
  uint32_t* hrec_arr = l ? p.h1 : p.h0;
  float* cst = p.c + ((size_t)(d * 2 + l) << 16);
  __syncthreads();

  for (int ph = 0; ph < NPHASE; ++ph) {
    const int t = l ? (ph - 1) : ph;
    if ((unsigned)t < (unsigned)S_LEN) {
      const int par = t & 1, prev = par ^ 1;
      const int td = d ? (S_LEN - 1 - t) : t;
      const uint32_t* hA = hrec_arr + ((size_t)(d * 2 + prev) << 16);
      const uint32_t* hI = p.h0 + ((size_t)(d * 2 + par) << 16);

      const f32x4 zero = {0.f, 0.f, 0.f, 0.f};
      f32x4 acc[3][2];
      #pragma unroll
      for (int g = 0; g < 3; ++g) { acc[g][0] = zero; acc[g][1] = zero; }

      // ---- recurrent half (LDS weights), split-f16 A ----
      #pragma unroll
      for (int kci = 0; kci < 8; ++kci) {
        const int kc = kq * 8 + kci;
        const int kk = kc * 32 + lg * 8;
        half8 hi[2], lo[2];
        #pragma unroll
        for (int mt = 0; mt < 2; ++mt) {
          const int row = mg * 32 + mt * 16 + lr;
          const uint4* ap = (const uint4*)(hA + (size_t)row * 1024 + kk);
          unpack8(ap[0], ap[1], hi[mt], lo[mt]);
        }
        #pragma unroll
        for (int g = 0; g < 3; ++g) {
          const half8 bf = *(const half8*)(wlds + ((size_t)(g * 32 + kc) * 64 + l64) * 8);
          acc[g][0] = __builtin_amdgcn_mfma_f32_16x16x32_f16(hi[0], bf, acc[g][0], 0, 0, 0);
          acc[g][1] = __builtin_amdgcn_mfma_f32_16x16x32_f16(hi[1], bf, acc[g][1], 0, 0, 0);
          acc[g][0] = __builtin_amdgcn_mfma_f32_16x16x32_f16(lo[0], bf, acc[g][0], 0, 0, 0);
          acc[g][1] = __builtin_amdgcn_mfma_f32_16x16x32_f16(lo[1], bf, acc[g][1], 0, 0, 0);
        }
      }
      // ---- input half (L2-streamed weights) ----
      if (l == 0) {
        #pragma unroll
        for (int kci = 0; kci < 8; ++kci) {
          const int kc = kq * 8 + kci;
          const int kk = kc * 32 + lg * 8;
          half8 xa[2];
          #pragma unroll
          for (int mt = 0; mt < 2; ++mt) {
            const int row = mg * 32 + mt * 16 + lr;
            xa[mt] = *(const half8*)(p.x16 + ((size_t)row * S_LEN + td) * 1024 + kk);
          }
          #pragma unroll
          for (int g = 0; g < 3; ++g) {
            const half8 bf = *(const half8*)(wtile + ((size_t)(g * 32 + kc) * 64 + l64) * 8);
            acc[g][0] = __builtin_amdgcn_mfma_f32_16x16x32_f16(xa[0], bf, acc[g][0], 0, 0, 0);
            acc[g][1] = __builtin_amdgcn_mfma_f32_16x16x32_f16(xa[1], bf, acc[g][1], 0, 0, 0);
          }
        }
      } else {
        #pragma unroll
        for (int kci = 0; kci < 8; ++kci) {
          const int kc = kq * 8 + kci;
          const int kk = kc * 32 + lg * 8;
          half8 hi[2], lo[2];
          #pragma unroll
          for (int mt = 0; mt < 2; ++mt) {
            const int row = mg * 32 + mt * 16 + lr;
            const uint4* ap = (const uint4*)(hI + (size_t)row * 1024 + kk);
            unpack8(ap[0], ap[1], hi[mt], lo[mt]);
          }
          #pragma unroll
          for (int g = 0; g < 3; ++g) {
            const half8 bf = *(const half8*)(wtile + ((size_t)(g * 32 + kc) * 64 + l64) * 8);
            acc[g][0] = __builtin_amdgcn_mfma_f32_16x16x32_f16(hi[0], bf, acc[g][0], 0, 0, 0);
            acc[g][1] = __builtin_amdgcn_mfma_f32_16x16x32_f16(hi[1], bf, acc[g][1], 0, 0, 0);
            acc[g][0] = __builtin_amdgcn_mfma_f32_16x16x32_f16(lo[0], bf, acc[g][0], 0, 0, 0);
            acc[g][1] = __builtin_amdgcn_mfma_f32_16x16x32_f16(lo[1], bf, acc[g][1], 0, 0, 0);
          }
        }
      }

      // ---- reduce kq partials ----
      #pragma unroll
      for (int g = 0; g < 3; ++g)
        #pragma unroll
        for (int mt = 0; mt < 2; ++mt)
          #pragma unroll
          for (int pp = 0; pp < 4; ++pp)
            pre[(((kq * 3 + g) * 64) + (mg * 2 + mt) * 16 + lg * 4 + pp) * 16 + lr] =
                acc[g][mt][pp];
      __syncthreads();

      // ---- pointwise LSTM update ----
      uint32_t* hdst = hrec_arr + ((size_t)(d * 2 + par) << 16);
      #pragma unroll
      for (int rep = 0; rep < 2; ++rep) {
        const int e = tid + rep * 512;
        const int r = e >> 4, jj = e & 15;
        const int jg = j0 + jj;
        float fp = p.bias[d][0][l * E_SZ + jg];
        float ip = p.bias[d][1][l * E_SZ + jg];
        float cp = p.bias[d][2][l * E_SZ + jg];
        #pragma unroll
        for (int k = 0; k < 4; ++k) {
          fp += pre[((k * 3 + 0) * 64 + r) * 16 + jj];
          ip += pre[((k * 3 + 1) * 64 + r) * 16 + jj];
          cp += pre[((k * 3 + 2) * 64 + r) * 16 + jj];
        }
        const float fg = 1.f / (1.f + expf(-fp));
        const float ig = 1.f / (1.f + expf(-ip));
        const float gg = tanhf(cp);
        const float cold = cst[(size_t)r * 1024 + jg];
        const float cnew = cold * fg + ig * gg;
        const float hnew = tanhf(cnew) * fg;   // forget gate reused as output gate
        cst[(size_t)r * 1024 + jg] = cnew;
        hdst[(size_t)r * 1024 + jg] = pack_split(hnew);
        if (l) wred[r * 16 + jj] = hnew * p.wordW[d * E_SZ + jg];
      }
      if (l) {
        __syncthreads();
        if (tid < 64) {
          float s = 0.f;
          #pragma unroll
          for (int q = 0; q < 16; ++q) s += wred[tid * 16 + q];
          atomicAdd(&p.w[(size_t)tid * S_LEN + td], s);
        }
      }
    }

    // ---- per-direction device barrier (counter + release flag) ----
    __syncthreads();
    if (tid == 0) {
      __threadfence();
      int prev_cnt = __hip_atomic_fetch_add(p.bar_cnt + d, 1, __ATOMIC_ACQ_REL,
                                            __HIP_MEMORY_SCOPE_AGENT);
      if (prev_cnt == 128 * (ph + 1) - 1) {
        __hip_atomic_store(p.bar_flag + d, ph + 1, __ATOMIC_RELEASE,
                           __HIP_MEMORY_SCOPE_AGENT);
      } else {
        // bounded spin: converts any residency deadlock into fast wrong-finish
        int f, it = 0;
        do {
          __builtin_amdgcn_s_sleep(2);
          f = __hip_atomic_load(p.bar_flag + d, __ATOMIC_ACQUIRE,
                                __HIP_MEMORY_SCOPE_AGENT);
        } while (f < ph + 1 && ++it < (1 << 22));
      }
      __threadfence();
    }
    __syncthreads();
  }
}

__global__ __launch_bounds__(320)
void final_kernel(const float* w, const float* predW, const float* predb, float* out) {
  const int tid = threadIdx.x;
  if (tid >= B_SZ * NLBL) return;
  const int b = tid / NLBL, lab = tid % NLBL;
  float s = predb[lab];
  #pragma unroll 8
  for (int t = 0; t < S_LEN; ++t) s += w[b * S_LEN + t] * predW[t * NLBL + lab];
  out[tid] = s;
}

// ================= fallback path (proven round-2 kernels) =================
#define KC    128
#define NC    16
#define BKP   136
#define OFF_H0 0
#define OFF_H1 262144
#define OFF_C0 524288
#define OFF_C1 655360
#define OFF_W  786432
#define WS_TOTAL 794624

struct ParamsFB {
  const float* x;
  const float* W[2][3];
  const float* bias[2][3];
  const float* wordW;
  float* h0;
  float* h1;
  float* c0;
  float* c1;
  float* w;
};

__global__ __launch_bounds__(256)
void init_fb(float* ws, const float* hs, const float* cs, const float* wordb) {
  size_t i = (size_t)blockIdx.x * 256 + threadIdx.x;
  if (i < OFF_C0) {
    size_t be = i & (size_t)(B_SZ * E_SZ - 1);
    ws[i] = hs[be];
  } else if (i < OFF_W) {
    size_t be = (i - OFF_C0) & (size_t)(B_SZ * E_SZ - 1);
    ws[i] = cs[be];
  } else if (i < WS_TOTAL) {
    ws[i] = wordb[0];
  }
}

template<int LAYER>
__global__ __launch_bounds__(512)
void step_fb(ParamsFB p, int t) {
  __shared__ __align__(16) unsigned char lds_raw[53248];
  _Float16* BtBase = (_Float16*)lds_raw;
  float* pre = (float*)lds_raw;
  float* wcs = (float*)(lds_raw + 49152);

  const int tid = threadIdx.x;
  const int l = tid & 63;
  const int lr = l & 15;
  const int lg = l >> 4;
  const int wv = tid >> 6;
  const int kq = wv & 3;
  const int mg = wv >> 2;

  const int blk = blockIdx.x;
  const int jg = blk & 63;
  const int d = blk >> 6;
  const int j0 = jg * 16;
  const int td = d ? (S_LEN - 1 - t) : t;
  const int cur = t & 1, nxt = cur ^ 1;

  const float* hsrc = (LAYER == 0 ? p.h0 : p.h1) + (size_t)(d * 2 + cur) * (B_SZ * E_SZ);
  const float* isrc = (LAYER == 0) ? p.x : p.h0 + (size_t)(d * 2 + nxt) * (B_SZ * E_SZ);
  const float* Wg0 = p.W[d][0] + (size_t)LAYER * 2 * E_SZ * E_SZ;
  const float* Wg1 = p.W[d][1] + (size_t)LAYER * 2 * E_SZ * E_SZ;
  const float* Wg2 = p.W[d][2] + (size_t)LAYER * 2 * E_SZ * E_SZ;

  auto loadA = [&](int c, float4 dst[2][2]) {
    const int kk = c * KC + kq * 32 + lg * 8;
    #pragma unroll
    for (int mi = 0; mi < 2; ++mi) {
      const int row = (mg * 2 + mi) * 16 + lr;
      const float* ptr;
      if (kk < E_SZ) ptr = hsrc + (size_t)row * E_SZ + kk;
      else if (LAYER == 0) ptr = isrc + ((size_t)row * S_LEN + td) * E_SZ + (kk - E_SZ);
      else ptr = isrc + (size_t)row * E_SZ + (kk - E_SZ);
      dst[mi][0] = *(const float4*)ptr;
      dst[mi][1] = *(const float4*)(ptr + 4);
    }
  };
  auto loadB = [&](int c, float4 breg[3]) {
    #pragma unroll
    for (int it = 0; it < 3; ++it) {
      const int idx = tid + it * 512;
      const int row = idx >> 2;
      const int g = row >> 7;
      const int kk = row & 127;
      const int q = idx & 3;
      const float* W = (g == 0 ? Wg0 : (g == 1 ? Wg1 : Wg2));
      breg[it] = *(const float4*)(W + (size_t)(c * KC + kk) * E_SZ + j0 + q * 4);
    }
  };
  auto writeB = [&](const float4 breg[3], int buf) {
    _Float16* Bt = BtBase + buf * (48 * BKP);
    #pragma unroll
    for (int it = 0; it < 3; ++it) {
      const int idx = tid + it * 512;
      const int row = idx >> 2;
      const int g = row >> 7;
      const int kk = row & 127;
      const int q = idx & 3;
      #pragma unroll
      for (int jj = 0; jj < 4; ++jj)
        Bt[(g * 16 + q * 4 + jj) * BKP + kk] = (_Float16)breg[it][jj];
    }
  };

  float4 aCur[2][2], aNxt[2][2];
  float4 breg[3];
  loadB(0, breg);
  loadA(0, aCur);
  writeB(breg, 0);
  __syncthreads();

  const f32x4 zero = {0.f, 0.f, 0.f, 0.f};
  f32x4 acc[3][2];
  #pragma unroll
  for (int g = 0; g < 3; ++g) { acc[g][0] = zero; acc[g][1] = zero; }

  #pragma unroll
  for (int c = 0; c < NC; ++c) {
    half8 a1[2], a2[2];
    #pragma unroll
    for (int mi = 0; mi < 2; ++mi) {
      #pragma unroll
      for (int i = 0; i < 8; ++i) {
        const float v = (i < 4) ? aCur[mi][0][i] : aCur[mi][1][i - 4];
        const _Float16 h = (_Float16)v;
        a1[mi][i] = h;
        a2[mi][i] = (_Float16)(v - (float)h);
      }
    }
    if (c + 1 < NC) { loadB(c + 1, breg); loadA(c + 1, aNxt); }

    const _Float16* BtR = BtBase + (c & 1) * (48 * BKP) + kq * 32 + lg * 8;
    half8 bf[3];
    #pragma unroll
    for (int g = 0; g < 3; ++g)
      bf[g] = *(const half8*)(BtR + (g * 16 + lr) * BKP);

    #pragma unroll
    for (int g = 0; g < 3; ++g) {
      acc[g][0] = __builtin_amdgcn_mfma_f32_16x16x32_f16(a1[0], bf[g], acc[g][0], 0, 0, 0);
      acc[g][1] = __builtin_amdgcn_mfma_f32_16x16x32_f16(a1[1], bf[g], acc[g][1], 0, 0, 0);
    }
    #pragma unroll
    for (int g = 0; g < 3; ++g) {
      acc[g][0] = __builtin_amdgcn_mfma_f32_16x16x32_f16(a2[0], bf[g], acc[g][0], 0, 0, 0);
      acc[g][1] = __builtin_amdgcn_mfma_f32_16x16x32_f16(a2[1], bf[g], acc[g][1], 0, 0, 0);
    }

    if (c + 1 < NC) {
      writeB(breg, (c + 1) & 1);
      __syncthreads();
      #pragma unroll
      for (int mi = 0; mi < 2; ++mi) {
        aCur[mi][0] = aNxt[mi][0];
        aCur[mi][1] = aNxt[mi][1];
      }
    }
  }

  __syncthreads();
  #pragma unroll
  for (int g = 0; g < 3; ++g)
    #pragma unroll
    for (int mi = 0; mi < 2; ++mi)
      #pragma unroll
      for (int pp = 0; pp < 4; ++pp)
        pre[(((kq * 3 + g) * 64) + (mg * 2 + mi) * 16 + lg * 4 + pp) * 16 + lr] =
            acc[g][mi][pp];
  __syncthreads();

  float* cstf = (LAYER == 0 ? p.c0 : p.c1) + (size_t)d * (B_SZ * E_SZ);
  float* hdst = (LAYER == 0 ? p.h0 : p.h1) + (size_t)(d * 2 + nxt) * (B_SZ * E_SZ);

  #pragma unroll
  for (int rep = 0; rep < 2; ++rep) {
    const int e = tid + rep * 512;
    const int r = e >> 4;
    const int j = e & 15;
    const int jglob = j0 + j;
    float fp = p.bias[d][0][LAYER * E_SZ + jglob];
    float ip = p.bias[d][1][LAYER * E_SZ + jglob];
    float cp = p.bias[d][2][LAYER * E_SZ + jglob];
    #pragma unroll
    for (int k = 0; k < 4; ++k) {
      fp += pre[((k * 3 + 0) * 64 + r) * 16 + j];
      ip += pre[((k * 3 + 1) * 64 + r) * 16 + j];
      cp += pre[((k * 3 + 2) * 64 + r) * 16 + j];
    }
    const float fg = 1.f / (1.f + expf(-fp));
    const float ig = 1.f / (1.f + expf(-ip));
    const float gg = tanhf(cp);
    const float cold = cstf[(size_t)r * E_SZ + jglob];
    const float cnew = cold * fg + ig * gg;
    const float hnew = tanhf(cnew) * fg;
    cstf[(size_t)r * E_SZ + jglob] = cnew;
    hdst[(size_t)r * E_SZ + jglob] = hnew;
    if (LAYER == 1) wcs[r * 16 + j] = hnew * p.wordW[(size_t)d * E_SZ + jglob];
  }

  if (LAYER == 1) {
    __syncthreads();
    if (tid < 64) {
      float s = 0.f;
      #pragma unroll
      for (int q = 0; q < 16; ++q) s += wcs[tid * 16 + q];
      atomicAdd(&p.w[(size_t)tid * S_LEN + td], s);
    }
  }
}

// ================= launcher =================
extern "C" void kernel_launch(void* const* d_in, const int* in_sizes, int n_in,
                              void* d_out, int out_size, void* d_ws, size_t ws_size,
                              hipStream_t stream) {
  char* ws = (char*)d_ws;

  if (ws_size >= WS_NEED) {
    PP p;
    p.x = (const float*)d_in[0];
    p.W[0][0] = (const float*)d_in[5];  p.bias[0][0] = (const float*)d_in[6];
    p.W[0][1] = (const float*)d_in[7];  p.bias[0][1] = (const float*)d_in[8];
    p.W[0][2] = (const float*)d_in[9];  p.bias[0][2] = (const float*)d_in[10];
    p.W[1][0] = (const float*)d_in[11]; p.bias[1][0] = (const float*)d_in[12];
    p.W[1][1] = (const float*)d_in[13]; p.bias[1][1] = (const float*)d_in[14];
    p.W[1][2] = (const float*)d_in[15]; p.bias[1][2] = (const float*)d_in[16];
    p.wordW = (const float*)d_in[17];
    p.wrec = (_Float16*)(ws + WOFF_WREC);
    p.winp = (_Float16*)(ws + WOFF_WINP);
    p.x16  = (_Float16*)(ws + WOFF_X16);
    p.h0   = (uint32_t*)(ws + WOFF_H0);
    p.h1   = (uint32_t*)(ws + WOFF_H1);
    p.c    = (float*)(ws + WOFF_C);
    p.w    = (float*)(ws + WOFF_W);
    p.bar_cnt  = (int*)(ws + WOFF_BAR);
    p.bar_flag = (int*)(ws + WOFF_BAR) + 2;

    hipFuncSetAttribute((const void*)lstm_persist,
                        hipFuncAttributeMaxDynamicSharedMemorySize, 151552);

    conv_w_kernel<<<1536, 256, 0, stream>>>(p);
    conv_x_kernel<<<4096, 256, 0, stream>>>(p.x, p.x16);
    init2_kernel<<<(INIT_TOTAL + 255) / 256, 256, 0, stream>>>(
        p, (const float*)d_in[2], (const float*)d_in[1], (const float*)d_in[18]);
    lstm_persist<<<256, 512, 151552, stream>>>(p);
    final_kernel<<<1, 320, 0, stream>>>(p.w, (const float*)d_in[19],
                                        (const float*)d_in[20], (float*)d_out);
  } else {
    float* wsf = (float*)d_ws;
    ParamsFB p;
    p.x = (const float*)d_in[0];
    p.W[0][0] = (const float*)d_in[5];  p.bias[0][0] = (const float*)d_in[6];
    p.W[0][1] = (const float*)d_in[7];  p.bias[0][1] = (const float*)d_in[8];
    p.W[0][2] = (const float*)d_in[9];  p.bias[0][2] = (const float*)d_in[10];
    p.W[1][0] = (const float*)d_in[11]; p.bias[1][0] = (const float*)d_in[12];
    p.W[1][1] = (const float*)d_in[13]; p.bias[1][1] = (const float*)d_in[14];
    p.W[1][2] = (const float*)d_in[15]; p.bias[1][2] = (const float*)d_in[16];
    p.wordW = (const float*)d_in[17];
    p.h0 = wsf + OFF_H0;
    p.h1 = wsf + OFF_H1;
    p.c0 = wsf + OFF_C0;
    p.c1 = wsf + OFF_C1;
    p.w  = wsf + OFF_W;

    init_fb<<<WS_TOTAL / 256, 256, 0, stream>>>(
        wsf, (const float*)d_in[2], (const float*)d_in[1], (const float*)d_in[18]);
    for (int t = 0; t < S_LEN; ++t) {
      step_fb<0><<<128, 512, 0, stream>>>(p, t);
      step_fb<1><<<128, 512, 0, stream>>>(p, t);
    }
    final_kernel<<<1, 320, 0, stream>>>(p.w, (const float*)d_in[19],
                                        (const float*)d_in[20], (float*)d_out);
  }
}

// Round 5
// 6953.965 us; speedup vs baseline: 3.2611x; 1.1615x over previous
//
#include <hip/hip_runtime.h>
#include <cstddef>
#include <cstdint>

typedef _Float16 half8 __attribute__((ext_vector_type(8)));
typedef float f32x4 __attribute__((ext_vector_type(4)));

#define S_LEN 128
#define B_SZ  64
#define E_SZ  1024
#define NLBL  5
#define NPHASE 129

// ---------------- new-path ws layout (bytes) ----------------
#define WOFF_WREC  0ull
#define WOFF_WINP  25165824ull
#define WOFF_X16   50331648ull
#define WOFF_H0    67108864ull
#define WOFF_H1    68157440ull
#define WOFF_C     69206016ull
#define WOFF_W     70254592ull
#define WOFF_WPART 70287360ull
#define WOFF_FLAGS 74481664ull   // 2*128 slots * 64B, then 2 rel slots * 64B
#define WS_NEED    74498176ull

// init element count: h0 262144 + h1 262144 + c 262144 + flags/rel 4128 ints
#define INIT_TOTAL 790560

struct PP {
  const float* x;
  const float* W[2][3];
  const float* bias[2][3];
  const float* wordW;
  _Float16* wrec;   // [ (d*2+l)*64 + j16 ][ g*16384 + (kc*64+lane)*8 + e ] f16
  _Float16* winp;
  _Float16* x16;    // [B][S][E] f16
  uint32_t* h0;     // [2d][2par][64][1024] packed (hi f16 low, lo f16 high)
  uint32_t* h1;
  float* c;         // [2d][2l][64][1024]
  float* w;         // [64][128]
  float* wpart;     // [2d][64 j16][128 t][64 b]
  int* flags;       // [2d][128] stride-16 ints, then rel[2] stride-16
  int* rel;
};

__device__ __forceinline__ uint32_t pack_split(float v) {
  _Float16 h = (_Float16)v;
  _Float16 l2 = (_Float16)(v - (float)h);
  return (uint32_t)__builtin_bit_cast(unsigned short, h) |
         ((uint32_t)__builtin_bit_cast(unsigned short, l2) << 16);
}

__device__ __forceinline__ void unpack8(uint4 a, uint4 b, half8& hi, half8& lo) {
  uint32_t v[8] = {a.x, a.y, a.z, a.w, b.x, b.y, b.z, b.w};
  #pragma unroll
  for (int i = 0; i < 8; ++i) {
    hi[i] = __builtin_bit_cast(_Float16, (unsigned short)(v[i] & 0xffffu));
    lo[i] = __builtin_bit_cast(_Float16, (unsigned short)(v[i] >> 16));
  }
}

// -------- conversion kernels (run every launch; deterministic) --------
__global__ __launch_bounds__(256)
void conv_w_kernel(PP p) {
  const int blk = blockIdx.x;           // (((d*2+l)*3+g)*64 + j16)*2 + part
  const int part = blk & 1;
  const int j16 = (blk >> 1) & 63;
  const int rest = blk >> 7;
  const int g = rest % 3;
  const int dl = rest / 3;
  const int l = dl & 1, d = dl >> 1;
  const int tid = threadIdx.x;
  const int l2 = tid & 63, kc0 = tid >> 6;
  const float* W = p.W[d][g] + (size_t)l * 2048 * 1024 + (size_t)(part ? 1024 : 0) * 1024;
  _Float16* out = (part ? p.winp : p.wrec) + (size_t)(dl * 64 + j16) * 49152 + (size_t)g * 16384;
  const int j = j16 * 16 + (l2 & 15);
  const int kbase = (l2 >> 4) * 8;
  #pragma unroll
  for (int ki = 0; ki < 8; ++ki) {
    const int kc = kc0 * 8 + ki;
    const int k0 = kc * 32 + kbase;
    half8 h;
    #pragma unroll
    for (int e2 = 0; e2 < 8; ++e2) h[e2] = (_Float16)W[(size_t)(k0 + e2) * 1024 + j];
    *(half8*)(out + ((size_t)kc * 64 + l2) * 8) = h;
  }
}

__global__ __launch_bounds__(256)
void conv_x_kernel(const float* x, _Float16* x16) {
  const size_t i8 = ((size_t)blockIdx.x * 256 + threadIdx.x) * 8;
  float4 a = *(const float4*)(x + i8);
  float4 b = *(const float4*)(x + i8 + 4);
  half8 h;
  h[0] = (_Float16)a.x; h[1] = (_Float16)a.y; h[2] = (_Float16)a.z; h[3] = (_Float16)a.w;
  h[4] = (_Float16)b.x; h[5] = (_Float16)b.y; h[6] = (_Float16)b.z; h[7] = (_Float16)b.w;
  *(half8*)(x16 + i8) = h;
}

__global__ __launch_bounds__(256)
void init2_kernel(PP p, const float* hs, const float* cs) {
  const size_t i = (size_t)blockIdx.x * 256 + threadIdx.x;
  if (i < 262144) {
    p.h0[i] = pack_split(hs[i & 65535]);
  } else if (i < 524288) {
    p.h1[i - 262144] = pack_split(hs[i & 65535]);
  } else if (i < 786432) {
    p.c[i - 524288] = cs[i & 65535];
  } else if (i < INIT_TOTAL) {
    p.flags[i - 786432] = 0;   // flags + rel contiguous
  }
}

// ---------------- persistent bidirectional LSTM ----------------
__global__ __launch_bounds__(512, 1)
void lstm_persist(PP p) {
  extern __shared__ char smem[];
  _Float16* wlds = (_Float16*)smem;            // 98304 B: rec weights
  float* pre  = (float*)(smem + 98304);        // 49152 B: kq partials
  float* wred = (float*)(smem + 147456);       // 4096 B: word-proj scratch

  const int tid = threadIdx.x;
  const int l64 = tid & 63, lr = l64 & 15, lg = l64 >> 4;
  const int wv = tid >> 6, kq = wv & 3, mg = wv >> 2;
  const int blk = blockIdx.x;
  const int j16 = blk & 63, l = (blk >> 6) & 1, d = blk >> 7;
  const int idx = blk & 127;                   // index within direction group
  const int j0 = j16 * 16;

  const size_t tileoff = (size_t)((d * 2 + l) * 64 + j16) * 49152;
  {
    const float4* src = (const float4*)(p.wrec + tileoff);
    float4* dst = (float4*)wlds;
    #pragma unroll
    for (int i = 0; i < 12; ++i) dst[tid + i * 512] = src[tid + i * 512];
  }
  const _Float16* wtile = p.winp + tileoff;
  uint32_t* hrec_arr = l ? p.h1 : p.h0;
  float* cst = p.c + ((size_t)(d * 2 + l) << 16);
  __syncthreads();

  for (int ph = 0; ph < NPHASE; ++ph) {
    const int t = l ? (ph - 1) : ph;
    if ((unsigned)t < (unsigned)S_LEN) {
      const int par = t & 1, prev = par ^ 1;
      const int td = d ? (S_LEN - 1 - t) : t;
      const uint32_t* hA = hrec_arr + ((size_t)(d * 2 + prev) << 16);
      const uint32_t* hI = p.h0 + ((size_t)(d * 2 + par) << 16);

      const f32x4 zero = {0.f, 0.f, 0.f, 0.f};
      f32x4 acc[3][2];
      #pragma unroll
      for (int g = 0; g < 3; ++g) { acc[g][0] = zero; acc[g][1] = zero; }

      // ---- recurrent half (LDS weights), split-f16 A ----
      #pragma unroll
      for (int kci = 0; kci < 8; ++kci) {
        const int kc = kq * 8 + kci;
        const int kk = kc * 32 + lg * 8;
        half8 hi[2], lo[2];
        #pragma unroll
        for (int mt = 0; mt < 2; ++mt) {
          const int row = mg * 32 + mt * 16 + lr;
          const uint4* ap = (const uint4*)(hA + (size_t)row * 1024 + kk);
          unpack8(ap[0], ap[1], hi[mt], lo[mt]);
        }
        #pragma unroll
        for (int g = 0; g < 3; ++g) {
          const half8 bf = *(const half8*)(wlds + ((size_t)(g * 32 + kc) * 64 + l64) * 8);
          acc[g][0] = __builtin_amdgcn_mfma_f32_16x16x32_f16(hi[0], bf, acc[g][0], 0, 0, 0);
          acc[g][1] = __builtin_amdgcn_mfma_f32_16x16x32_f16(hi[1], bf, acc[g][1], 0, 0, 0);
          acc[g][0] = __builtin_amdgcn_mfma_f32_16x16x32_f16(lo[0], bf, acc[g][0], 0, 0, 0);
          acc[g][1] = __builtin_amdgcn_mfma_f32_16x16x32_f16(lo[1], bf, acc[g][1], 0, 0, 0);
        }
      }
      // ---- input half (global weights) ----
      if (l == 0) {
        #pragma unroll
        for (int kci = 0; kci < 8; ++kci) {
          const int kc = kq * 8 + kci;
          const int kk = kc * 32 + lg * 8;
          half8 xa[2];
          #pragma unroll
          for (int mt = 0; mt < 2; ++mt) {
            const int row = mg * 32 + mt * 16 + lr;
            xa[mt] = *(const half8*)(p.x16 + ((size_t)row * S_LEN + td) * 1024 + kk);
          }
          #pragma unroll
          for (int g = 0; g < 3; ++g) {
            const half8 bf = *(const half8*)(wtile + ((size_t)(g * 32 + kc) * 64 + l64) * 8);
            acc[g][0] = __builtin_amdgcn_mfma_f32_16x16x32_f16(xa[0], bf, acc[g][0], 0, 0, 0);
            acc[g][1] = __builtin_amdgcn_mfma_f32_16x16x32_f16(xa[1], bf, acc[g][1], 0, 0, 0);
          }
        }
      } else {
        #pragma unroll
        for (int kci = 0; kci < 8; ++kci) {
          const int kc = kq * 8 + kci;
          const int kk = kc * 32 + lg * 8;
          half8 hi[2], lo[2];
          #pragma unroll
          for (int mt = 0; mt < 2; ++mt) {
            const int row = mg * 32 + mt * 16 + lr;
            const uint4* ap = (const uint4*)(hI + (size_t)row * 1024 + kk);
            unpack8(ap[0], ap[1], hi[mt], lo[mt]);
          }
          #pragma unroll
          for (int g = 0; g < 3; ++g) {
            const half8 bf = *(const half8*)(wtile + ((size_t)(g * 32 + kc) * 64 + l64) * 8);
            acc[g][0] = __builtin_amdgcn_mfma_f32_16x16x32_f16(hi[0], bf, acc[g][0], 0, 0, 0);
            acc[g][1] = __builtin_amdgcn_mfma_f32_16x16x32_f16(hi[1], bf, acc[g][1], 0, 0, 0);
            acc[g][0] = __builtin_amdgcn_mfma_f32_16x16x32_f16(lo[0], bf, acc[g][0], 0, 0, 0);
            acc[g][1] = __builtin_amdgcn_mfma_f32_16x16x32_f16(lo[1], bf, acc[g][1], 0, 0, 0);
          }
        }
      }

      // ---- reduce kq partials ----
      #pragma unroll
      for (int g = 0; g < 3; ++g)
        #pragma unroll
        for (int mt = 0; mt < 2; ++mt)
          #pragma unroll
          for (int pp = 0; pp < 4; ++pp)
            pre[(((kq * 3 + g) * 64) + (mg * 2 + mt) * 16 + lg * 4 + pp) * 16 + lr] =
                acc[g][mt][pp];
      __syncthreads();

      // ---- pointwise LSTM update ----
      uint32_t* hdst = hrec_arr + ((size_t)(d * 2 + par) << 16);
      #pragma unroll
      for (int rep = 0; rep < 2; ++rep) {
        const int e = tid + rep * 512;
        const int r = e >> 4, jj = e & 15;
        const int jg = j0 + jj;
        float fp = p.bias[d][0][l * E_SZ + jg];
        float ip = p.bias[d][1][l * E_SZ + jg];
        float cp = p.bias[d][2][l * E_SZ + jg];
        #pragma unroll
        for (int k = 0; k < 4; ++k) {
          fp += pre[((k * 3 + 0) * 64 + r) * 16 + jj];
          ip += pre[((k * 3 + 1) * 64 + r) * 16 + jj];
          cp += pre[((k * 3 + 2) * 64 + r) * 16 + jj];
        }
        const float fg = 1.f / (1.f + expf(-fp));
        const float ig = 1.f / (1.f + expf(-ip));
        const float gg = tanhf(cp);
        const float cold = cst[(size_t)r * 1024 + jg];
        const float cnew = cold * fg + ig * gg;
        const float hnew = tanhf(cnew) * fg;   // forget gate reused as output gate
        cst[(size_t)r * 1024 + jg] = cnew;
        hdst[(size_t)r * 1024 + jg] = pack_split(hnew);
        if (l) wred[r * 16 + jj] = hnew * p.wordW[d * E_SZ + jg];
      }
      if (l) {
        __syncthreads();
        if (tid < 64) {
          float s = 0.f;
          #pragma unroll
          for (int q = 0; q < 16; ++q) s += wred[tid * 16 + q];
          // private partial slice: no atomics
          p.wpart[((size_t)(d * 64 + j16) * S_LEN + td) * 64 + tid] = s;
        }
      }
    }

    // ---- per-direction device barrier: flag array + master + release ----
    __syncthreads();
    if (idx == 0) {
      // master: scan the 127 other blocks' flags in parallel
      if (tid >= 1 && tid < 128) {
        int f, it = 0;
        do {
          f = __hip_atomic_load(p.flags + (d * 128 + tid) * 16,
                                __ATOMIC_ACQUIRE, __HIP_MEMORY_SCOPE_AGENT);
          if (f >= ph + 1) break;
          __builtin_amdgcn_s_sleep(2);
        } while (++it < (1 << 22));
      }
      __syncthreads();
      if (tid == 0) {
        __threadfence();
        __hip_atomic_store(p.rel + d * 16, ph + 1, __ATOMIC_RELEASE,
                           __HIP_MEMORY_SCOPE_AGENT);
      }
    } else {
      if (tid == 0) {
        __threadfence();
        __hip_atomic_store(p.flags + (d * 128 + idx) * 16, ph + 1,
                           __ATOMIC_RELEASE, __HIP_MEMORY_SCOPE_AGENT);
        int f, it = 0;
        do {
          f = __hip_atomic_load(p.rel + d * 16, __ATOMIC_ACQUIRE,
                                __HIP_MEMORY_SCOPE_AGENT);
          if (f >= ph + 1) break;
          __builtin_amdgcn_s_sleep(2);
        } while (++it < (1 << 22));
      }
    }
    __syncthreads();
  }
}

// w[b][t] = word_b + sum over (d,j16) of wpart
__global__ __launch_bounds__(64)
void reduce_w_kernel(const float* wpart, const float* wordb, float* w) {
  const int t = blockIdx.x, b = threadIdx.x;
  float s = wordb[0];
  #pragma unroll 8
  for (int q = 0; q < 128; ++q)
    s += wpart[((size_t)q * S_LEN + t) * 64 + b];
  w[b * S_LEN + t] = s;
}

__global__ __launch_bounds__(320)
void final_kernel(const float* w, const float* predW, const float* predb, float* out) {
  const int tid = threadIdx.x;
  if (tid >= B_SZ * NLBL) return;
  const int b = tid / NLBL, lab = tid % NLBL;
  float s = predb[lab];
  #pragma unroll 8
  for (int t = 0; t < S_LEN; ++t) s += w[b * S_LEN + t] * predW[t * NLBL + lab];
  out[tid] = s;
}

// ================= fallback path (proven round-2 kernels) =================
#define KC    128
#define NC    16
#define BKP   136
#define OFF_H0 0
#define OFF_H1 262144
#define OFF_C0 524288
#define OFF_C1 655360
#define OFF_W  786432
#define WS_TOTAL 794624

struct ParamsFB {
  const float* x;
  const float* W[2][3];
  const float* bias[2][3];
  const float* wordW;
  float* h0;
  float* h1;
  float* c0;
  float* c1;
  float* w;
};

__global__ __launch_bounds__(256)
void init_fb(float* ws, const float* hs, const float* cs, const float* wordb) {
  size_t i = (size_t)blockIdx.x * 256 + threadIdx.x;
  if (i < OFF_C0) {
    size_t be = i & (size_t)(B_SZ * E_SZ - 1);
    ws[i] = hs[be];
  } else if (i < OFF_W) {
    size_t be = (i - OFF_C0) & (size_t)(B_SZ * E_SZ - 1);
    ws[i] = cs[be];
  } else if (i < WS_TOTAL) {
    ws[i] = wordb[0];
  }
}

template<int LAYER>
__global__ __launch_bounds__(512)
void step_fb(ParamsFB p, int t) {
  __shared__ __align__(16) unsigned char lds_raw[53248];
  _Float16* BtBase = (_Float16*)lds_raw;
  float* pre = (float*)lds_raw;
  float* wcs = (float*)(lds_raw + 49152);

  const int tid = threadIdx.x;
  const int l = tid & 63;
  const int lr = l & 15;
  const int lg = l >> 4;
  const int wv = tid >> 6;
  const int kq = wv & 3;
  const int mg = wv >> 2;

  const int blk = blockIdx.x;
  const int jg = blk & 63;
  const int d = blk >> 6;
  const int j0 = jg * 16;
  const int td = d ? (S_LEN - 1 - t) : t;
  const int cur = t & 1, nxt = cur ^ 1;

  const float* hsrc = (LAYER == 0 ? p.h0 : p.h1) + (size_t)(d * 2 + cur) * (B_SZ * E_SZ);
  const float* isrc = (LAYER == 0) ? p.x : p.h0 + (size_t)(d * 2 + nxt) * (B_SZ * E_SZ);
  const float* Wg0 = p.W[d][0] + (size_t)LAYER * 2 * E_SZ * E_SZ;
  const float* Wg1 = p.W[d][1] + (size_t)LAYER * 2 * E_SZ * E_SZ;
  const float* Wg2 = p.W[d][2] + (size_t)LAYER * 2 * E_SZ * E_SZ;

  auto loadA = [&](int c, float4 dst[2][2]) {
    const int kk = c * KC + kq * 32 + lg * 8;
    #pragma unroll
    for (int mi = 0; mi < 2; ++mi) {
      const int row = (mg * 2 + mi) * 16 + lr;
      const float* ptr;
      if (kk < E_SZ) ptr = hsrc + (size_t)row * E_SZ + kk;
      else if (LAYER == 0) ptr = isrc + ((size_t)row * S_LEN + td) * E_SZ + (kk - E_SZ);
      else ptr = isrc + (size_t)row * E_SZ + (kk - E_SZ);
      dst[mi][0] = *(const float4*)ptr;
      dst[mi][1] = *(const float4*)(ptr + 4);
    }
  };
  auto loadB = [&](int c, float4 breg[3]) {
    #pragma unroll
    for (int it = 0; it < 3; ++it) {
      const int idx2 = tid + it * 512;
      const int row = idx2 >> 2;
      const int g = row >> 7;
      const int kk = row & 127;
      const int q = idx2 & 3;
      const float* W = (g == 0 ? Wg0 : (g == 1 ? Wg1 : Wg2));
      breg[it] = *(const float4*)(W + (size_t)(c * KC + kk) * E_SZ + j0 + q * 4);
    }
  };
  auto writeB = [&](const float4 breg[3], int buf) {
    _Float16* Bt = BtBase + buf * (48 * BKP);
    #pragma unroll
    for (int it = 0; it < 3; ++it) {
      const int idx2 = tid + it * 512;
      const int row = idx2 >> 2;
      const int g = row >> 7;
      const int kk = row & 127;
      const int q = idx2 & 3;
      #pragma unroll
      for (int jj = 0; jj < 4; ++jj)
        Bt[(g * 16 + q * 4 + jj) * BKP + kk] = (_Float16)breg[it][jj];
    }
  };

  float4 aCur[2][2], aNxt[2][2];
  float4 breg[3];
  loadB(0, breg);
  loadA(0, aCur);
  writeB(breg, 0);
  __syncthreads();

  const f32x4 zero = {0.f, 0.f, 0.f, 0.f};
  f32x4 acc[3][2];
  #pragma unroll
  for (int g = 0; g < 3; ++g) { acc[g][0] = zero; acc[g][1] = zero; }

  #pragma unroll
  for (int c = 0; c < NC; ++c) {
    half8 a1[2], a2[2];
    #pragma unroll
    for (int mi = 0; mi < 2; ++mi) {
      #pragma unroll
      for (int i = 0; i < 8; ++i) {
        const float v = (i < 4) ? aCur[mi][0][i] : aCur[mi][1][i - 4];
        const _Float16 h = (_Float16)v;
        a1[mi][i] = h;
        a2[mi][i] = (_Float16)(v - (float)h);
      }
    }
    if (c + 1 < NC) { loadB(c + 1, breg); loadA(c + 1, aNxt); }

    const _Float16* BtR = BtBase + (c & 1) * (48 * BKP) + kq * 32 + lg * 8;
    half8 bf[3];
    #pragma unroll
    for (int g = 0; g < 3; ++g)
      bf[g] = *(const half8*)(BtR + (g * 16 + lr) * BKP);

    #pragma unroll
    for (int g = 0; g < 3; ++g) {
      acc[g][0] = __builtin_amdgcn_mfma_f32_16x16x32_f16(a1[0], bf[g], acc[g][0], 0, 0, 0);
      acc[g][1] = __builtin_amdgcn_mfma_f32_16x16x32_f16(a1[1], bf[g], acc[g][1], 0, 0, 0);
    }
    #pragma unroll
    for (int g = 0; g < 3; ++g) {
      acc[g][0] = __builtin_amdgcn_mfma_f32_16x16x32_f16(a2[0], bf[g], acc[g][0], 0, 0, 0);
      acc[g][1] = __builtin_amdgcn_mfma_f32_16x16x32_f16(a2[1], bf[g], acc[g][1], 0, 0, 0);
    }

    if (c + 1 < NC) {
      writeB(breg, (c + 1) & 1);
      __syncthreads();
      #pragma unroll
      for (int mi = 0; mi < 2; ++mi) {
        aCur[mi][0] = aNxt[mi][0];
        aCur[mi][1] = aNxt[mi][1];
      }
    }
  }

  __syncthreads();
  #pragma unroll
  for (int g = 0; g < 3; ++g)
    #pragma unroll
    for (int mi = 0; mi < 2; ++mi)
      #pragma unroll
      for (int pp = 0; pp < 4; ++pp)
        pre[(((kq * 3 + g) * 64) + (mg * 2 + mi) * 16 + lg * 4 + pp) * 16 + lr] =
            acc[g][mi][pp];
  __syncthreads();

  float* cstf = (LAYER == 0 ? p.c0 : p.c1) + (size_t)d * (B_SZ * E_SZ);
  float* hdst = (LAYER == 0 ? p.h0 : p.h1) + (size_t)(d * 2 + nxt) * (B_SZ * E_SZ);

  #pragma unroll
  for (int rep = 0; rep < 2; ++rep) {
    const int e = tid + rep * 512;
    const int r = e >> 4;
    const int j = e & 15;
    const int jglob = j0 + j;
    float fp = p.bias[d][0][LAYER * E_SZ + jglob];
    float ip = p.bias[d][1][LAYER * E_SZ + jglob];
    float cp = p.bias[d][2][LAYER * E_SZ + jglob];
    #pragma unroll
    for (int k = 0; k < 4; ++k) {
      fp += pre[((k * 3 + 0) * 64 + r) * 16 + j];
      ip += pre[((k * 3 + 1) * 64 + r) * 16 + j];
      cp += pre[((k * 3 + 2) * 64 + r) * 16 + j];
    }
    const float fg = 1.f / (1.f + expf(-fp));
    const float ig = 1.f / (1.f + expf(-ip));
    const float gg = tanhf(cp);
    const float cold = cstf[(size_t)r * E_SZ + jglob];
    const float cnew = cold * fg + ig * gg;
    const float hnew = tanhf(cnew) * fg;
    cstf[(size_t)r * E_SZ + jglob] = cnew;
    hdst[(size_t)r * E_SZ + jglob] = hnew;
    if (LAYER == 1) wcs[r * 16 + j] = hnew * p.wordW[(size_t)d * E_SZ + jglob];
  }

  if (LAYER == 1) {
    __syncthreads();
    if (tid < 64) {
      float s = 0.f;
      #pragma unroll
      for (int q = 0; q < 16; ++q) s += wcs[tid * 16 + q];
      atomicAdd(&p.w[(size_t)tid * S_LEN + td], s);
    }
  }
}

// ================= launcher =================
extern "C" void kernel_launch(void* const* d_in, const int* in_sizes, int n_in,
                              void* d_out, int out_size, void* d_ws, size_t ws_size,
                              hipStream_t stream) {
  char* ws = (char*)d_ws;

  if (ws_size >= WS_NEED) {
    PP p;
    p.x = (const float*)d_in[0];
    p.W[0][0] = (const float*)d_in[5];  p.bias[0][0] = (const float*)d_in[6];
    p.W[0][1] = (const float*)d_in[7];  p.bias[0][1] = (const float*)d_in[8];
    p.W[0][2] = (const float*)d_in[9];  p.bias[0][2] = (const float*)d_in[10];
    p.W[1][0] = (const float*)d_in[11]; p.bias[1][0] = (const float*)d_in[12];
    p.W[1][1] = (const float*)d_in[13]; p.bias[1][1] = (const float*)d_in[14];
    p.W[1][2] = (const float*)d_in[15]; p.bias[1][2] = (const float*)d_in[16];
    p.wordW = (const float*)d_in[17];
    p.wrec  = (_Float16*)(ws + WOFF_WREC);
    p.winp  = (_Float16*)(ws + WOFF_WINP);
    p.x16   = (_Float16*)(ws + WOFF_X16);
    p.h0    = (uint32_t*)(ws + WOFF_H0);
    p.h1    = (uint32_t*)(ws + WOFF_H1);
    p.c     = (float*)(ws + WOFF_C);
    p.w     = (float*)(ws + WOFF_W);
    p.wpart = (float*)(ws + WOFF_WPART);
    p.flags = (int*)(ws + WOFF_FLAGS);
    p.rel   = (int*)(ws + WOFF_FLAGS) + 2 * 128 * 16;

    hipFuncSetAttribute((const void*)lstm_persist,
                        hipFuncAttributeMaxDynamicSharedMemorySize, 151552);

    conv_w_kernel<<<1536, 256, 0, stream>>>(p);
    conv_x_kernel<<<4096, 256, 0, stream>>>(p.x, p.x16);
    init2_kernel<<<(INIT_TOTAL + 255) / 256, 256, 0, stream>>>(
        p, (const float*)d_in[2], (const float*)d_in[1]);
    lstm_persist<<<256, 512, 151552, stream>>>(p);
    reduce_w_kernel<<<128, 64, 0, stream>>>(p.wpart, (const float*)d_in[18], p.w);
    final_kernel<<<1, 320, 0, stream>>>(p.w, (const float*)d_in[19],
                                        (const float*)d_in[20], (float*)d_out);
  } else {
    float* wsf = (float*)d_ws;
    ParamsFB p;
    p.x = (const float*)d_in[0];
    p.W[0][0] = (const float*)d_in[5];  p.bias[0][0] = (const float*)d_in[6];
    p.W[0][1] = (const float*)d_in[7];  p.bias[0][1] = (const float*)d_in[8];
    p.W[0][2] = (const float*)d_in[9];  p.bias[0][2] = (const float*)d_in[10];
    p.W[1][0] = (const float*)d_in[11]; p.bias[1][0] = (const float*)d_in[12];
    p.W[1][1] = (const float*)d_in[13]; p.bias[1][1] = (const float*)d_in[14];
    p.W[1][2] = (const float*)d_in[15]; p.bias[1][2] = (const float*)d_in[16];
    p.wordW = (const float*)d_in[17];
    p.h0 = wsf + OFF_H0;
    p.h1 = wsf + OFF_H1;
    p.c0 = wsf + OFF_C0;
    p.c1 = wsf + OFF_C1;
    p.w  = wsf + OFF_W;

    init_fb<<<WS_TOTAL / 256, 256, 0, stream>>>(
        wsf, (const float*)d_in[2], (const float*)d_in[1], (const float*)d_in[18]);
    for (int t = 0; t < S_LEN; ++t) {
      step_fb<0><<<128, 512, 0, stream>>>(p, t);
      step_fb<1><<<128, 512, 0, stream>>>(p, t);
    }
    final_kernel<<<1, 320, 0, stream>>>(p.w, (const float*)d_in[19],
                                        (const float*)d_in[20], (float*)d_out);
  }
}

// Round 6
// 2717.186 us; speedup vs baseline: 8.3459x; 2.5593x over previous
//
#include <hip/hip_runtime.h>
#include <cstddef>
#include <cstdint>

typedef _Float16 half8 __attribute__((ext_vector_type(8)));
typedef float f32x4 __attribute__((ext_vector_type(4)));

#define S_LEN 128
#define B_SZ  64
#define E_SZ  1024
#define NLBL  5
#define NPHASE 129

// ---------------- new-path ws layout (bytes) ----------------
#define WOFF_WREC  0ull
#define WOFF_WINP  25165824ull
#define WOFF_X16   50331648ull
#define WOFF_H0    67108864ull
#define WOFF_H1    68157440ull
#define WOFF_C     69206016ull
#define WOFF_W     70254592ull
#define WOFF_WPART 70287360ull
#define WOFF_FLAGS 74481664ull   // 2*128 slots * 64B, then 2 rel slots * 64B
#define WS_NEED    74498176ull

// init element count: h0 262144 + h1 262144 + c 262144 + flags/rel 4128 ints
#define INIT_TOTAL 790560

struct PP {
  const float* x;
  const float* W[2][3];
  const float* bias[2][3];
  const float* wordW;
  _Float16* wrec;   // [ (d*2+l)*64 + j16 ][ g*16384 + (kc*64+lane)*8 + e ] f16
  _Float16* winp;
  _Float16* x16;    // [B][S][E] f16
  uint32_t* h0;     // [2d][2par][64][1024] packed (hi f16 low, lo f16 high)
  uint32_t* h1;
  float* c;         // [2d][2l][64][1024]
  float* w;         // [64][128]
  float* wpart;     // [2d][64 j16][128 t][64 b]
  int* flags;       // [2d][128] stride-16 ints, then rel[2] stride-16
  int* rel;
};

__device__ __forceinline__ uint32_t pack_split(float v) {
  _Float16 h = (_Float16)v;
  _Float16 l2 = (_Float16)(v - (float)h);
  return (uint32_t)__builtin_bit_cast(unsigned short, h) |
         ((uint32_t)__builtin_bit_cast(unsigned short, l2) << 16);
}

__device__ __forceinline__ void unpack8(uint4 a, uint4 b, half8& hi, half8& lo) {
  uint32_t v[8] = {a.x, a.y, a.z, a.w, b.x, b.y, b.z, b.w};
  #pragma unroll
  for (int i = 0; i < 8; ++i) {
    hi[i] = __builtin_bit_cast(_Float16, (unsigned short)(v[i] & 0xffffu));
    lo[i] = __builtin_bit_cast(_Float16, (unsigned short)(v[i] >> 16));
  }
}

// 8 coherence-point (sc0 sc1) 16B loads, wait inside the asm block: the
// results are data-dependent outputs, so no compiler-reordering hazard.
__device__ __forceinline__ void coh_load8(
    const uint32_t* p0, const uint32_t* p1, const uint32_t* p2, const uint32_t* p3,
    const uint32_t* p4, const uint32_t* p5, const uint32_t* p6, const uint32_t* p7,
    uint4& q0, uint4& q1, uint4& q2, uint4& q3,
    uint4& q4, uint4& q5, uint4& q6, uint4& q7) {
  asm volatile(
      "global_load_dwordx4 %0, %8, off sc0 sc1\n\t"
      "global_load_dwordx4 %1, %9, off sc0 sc1\n\t"
      "global_load_dwordx4 %2, %10, off sc0 sc1\n\t"
      "global_load_dwordx4 %3, %11, off sc0 sc1\n\t"
      "global_load_dwordx4 %4, %12, off sc0 sc1\n\t"
      "global_load_dwordx4 %5, %13, off sc0 sc1\n\t"
      "global_load_dwordx4 %6, %14, off sc0 sc1\n\t"
      "global_load_dwordx4 %7, %15, off sc0 sc1\n\t"
      "s_waitcnt vmcnt(0)"
      : "=&v"(q0), "=&v"(q1), "=&v"(q2), "=&v"(q3),
        "=&v"(q4), "=&v"(q5), "=&v"(q6), "=&v"(q7)
      : "v"(p0), "v"(p1), "v"(p2), "v"(p3), "v"(p4), "v"(p5), "v"(p6), "v"(p7)
      : "memory");
}

// -------- conversion kernels (run every launch; deterministic) --------
__global__ __launch_bounds__(256)
void conv_w_kernel(PP p) {
  const int blk = blockIdx.x;           // (((d*2+l)*3+g)*64 + j16)*2 + part
  const int part = blk & 1;
  const int j16 = (blk >> 1) & 63;
  const int rest = blk >> 7;
  const int g = rest % 3;
  const int dl = rest / 3;
  const int l = dl & 1, d = dl >> 1;
  const int tid = threadIdx.x;
  const int l2 = tid & 63, kc0 = tid >> 6;
  const float* W = p.W[d][g] + (size_t)l * 2048 * 1024 + (size_t)(part ? 1024 : 0) * 1024;
  _Float16* out = (part ? p.winp : p.wrec) + (size_t)(dl * 64 + j16) * 49152 + (size_t)g * 16384;
  const int j = j16 * 16 + (l2 & 15);
  const int kbase = (l2 >> 4) * 8;
  #pragma unroll
  for (int ki = 0; ki < 8; ++ki) {
    const int kc = kc0 * 8 + ki;
    const int k0 = kc * 32 + kbase;
    half8 h;
    #pragma unroll
    for (int e2 = 0; e2 < 8; ++e2) h[e2] = (_Float16)W[(size_t)(k0 + e2) * 1024 + j];
    *(half8*)(out + ((size_t)kc * 64 + l2) * 8) = h;
  }
}

__global__ __launch_bounds__(256)
void conv_x_kernel(const float* x, _Float16* x16) {
  const size_t i8 = ((size_t)blockIdx.x * 256 + threadIdx.x) * 8;
  float4 a = *(const float4*)(x + i8);
  float4 b = *(const float4*)(x + i8 + 4);
  half8 h;
  h[0] = (_Float16)a.x; h[1] = (_Float16)a.y; h[2] = (_Float16)a.z; h[3] = (_Float16)a.w;
  h[4] = (_Float16)b.x; h[5] = (_Float16)b.y; h[6] = (_Float16)b.z; h[7] = (_Float16)b.w;
  *(half8*)(x16 + i8) = h;
}

__global__ __launch_bounds__(256)
void init2_kernel(PP p, const float* hs, const float* cs) {
  const size_t i = (size_t)blockIdx.x * 256 + threadIdx.x;
  if (i < 262144) {
    p.h0[i] = pack_split(hs[i & 65535]);
  } else if (i < 524288) {
    p.h1[i - 262144] = pack_split(hs[i & 65535]);
  } else if (i < 786432) {
    p.c[i - 524288] = cs[i & 65535];
  } else if (i < INIT_TOTAL) {
    p.flags[i - 786432] = 0;   // flags + rel contiguous
  }
}

// ---------------- persistent bidirectional LSTM ----------------
__global__ __launch_bounds__(512, 1)
void lstm_persist(PP p) {
  extern __shared__ char smem[];
  _Float16* wlds = (_Float16*)smem;            // 98304 B: rec weights
  float* pre  = (float*)(smem + 98304);        // 49152 B: kq partials
  float* wred = (float*)(smem + 147456);       // 4096 B: word-proj scratch

  const int tid = threadIdx.x;
  const int l64 = tid & 63, lr = l64 & 15, lg = l64 >> 4;
  const int wv = tid >> 6, kq = wv & 3, mg = wv >> 2;
  const int blk = blockIdx.x;
  const int j16 = blk & 63, l = (blk >> 6) & 1, d = blk >> 7;
  const int idx = blk & 127;                   // index within direction group
  const int j0 = j16 * 16;

  const size_t tileoff = (size_t)((d * 2 + l) * 64 + j16) * 49152;
  {
    const float4* src = (const float4*)(p.wrec + tileoff);
    float4* dst = (float4*)wlds;
    #pragma unroll
    for (int i = 0; i < 12; ++i) dst[tid + i * 512] = src[tid + i * 512];
  }
  const _Float16* wtile = p.winp + tileoff;
  uint32_t* hrec_arr = l ? p.h1 : p.h0;
  float* cst = p.c + ((size_t)(d * 2 + l) << 16);
  __syncthreads();

  for (int ph = 0; ph < NPHASE; ++ph) {
    const int t = l ? (ph - 1) : ph;
    if ((unsigned)t < (unsigned)S_LEN) {
      const int par = t & 1, prev = par ^ 1;
      const int td = d ? (S_LEN - 1 - t) : t;
      const uint32_t* hA = hrec_arr + ((size_t)(d * 2 + prev) << 16);
      const uint32_t* hI = p.h0 + ((size_t)(d * 2 + par) << 16);

      const f32x4 zero = {0.f, 0.f, 0.f, 0.f};
      f32x4 acc[3][2];
      #pragma unroll
      for (int g = 0; g < 3; ++g) { acc[g][0] = zero; acc[g][1] = zero; }

      const uint32_t* r0 = hA + (size_t)(mg * 32 + lr) * 1024;
      const uint32_t* r1 = hA + (size_t)(mg * 32 + 16 + lr) * 1024;

      // ---- recurrent half (LDS weights), split-f16 A, coherent h loads ----
      #pragma unroll
      for (int ch = 0; ch < 4; ++ch) {
        const int kcA = kq * 8 + ch * 2;
        const int kkA = kcA * 32 + lg * 8;
        const int kkB = kkA + 32;
        uint4 q0, q1, q2, q3, q4, q5, q6, q7;
        coh_load8(r0 + kkA, r0 + kkA + 4, r1 + kkA, r1 + kkA + 4,
                  r0 + kkB, r0 + kkB + 4, r1 + kkB, r1 + kkB + 4,
                  q0, q1, q2, q3, q4, q5, q6, q7);
        #pragma unroll
        for (int s = 0; s < 2; ++s) {
          const int kc = kcA + s;
          half8 hi[2], lo[2];
          unpack8(s ? q4 : q0, s ? q5 : q1, hi[0], lo[0]);
          unpack8(s ? q6 : q2, s ? q7 : q3, hi[1], lo[1]);
          #pragma unroll
          for (int g = 0; g < 3; ++g) {
            const half8 bf = *(const half8*)(wlds + ((size_t)(g * 32 + kc) * 64 + l64) * 8);
            acc[g][0] = __builtin_amdgcn_mfma_f32_16x16x32_f16(hi[0], bf, acc[g][0], 0, 0, 0);
            acc[g][1] = __builtin_amdgcn_mfma_f32_16x16x32_f16(hi[1], bf, acc[g][1], 0, 0, 0);
            acc[g][0] = __builtin_amdgcn_mfma_f32_16x16x32_f16(lo[0], bf, acc[g][0], 0, 0, 0);
            acc[g][1] = __builtin_amdgcn_mfma_f32_16x16x32_f16(lo[1], bf, acc[g][1], 0, 0, 0);
          }
        }
      }
      // ---- input half ----
      if (l == 0) {
        // x16: read-only, plain cached loads
        #pragma unroll
        for (int kci = 0; kci < 8; ++kci) {
          const int kc = kq * 8 + kci;
          const int kk = kc * 32 + lg * 8;
          half8 xa[2];
          #pragma unroll
          for (int mt = 0; mt < 2; ++mt) {
            const int row = mg * 32 + mt * 16 + lr;
            xa[mt] = *(const half8*)(p.x16 + ((size_t)row * S_LEN + td) * 1024 + kk);
          }
          #pragma unroll
          for (int g = 0; g < 3; ++g) {
            const half8 bf = *(const half8*)(wtile + ((size_t)(g * 32 + kc) * 64 + l64) * 8);
            acc[g][0] = __builtin_amdgcn_mfma_f32_16x16x32_f16(xa[0], bf, acc[g][0], 0, 0, 0);
            acc[g][1] = __builtin_amdgcn_mfma_f32_16x16x32_f16(xa[1], bf, acc[g][1], 0, 0, 0);
          }
        }
      } else {
        const uint32_t* s0 = hI + (size_t)(mg * 32 + lr) * 1024;
        const uint32_t* s1 = hI + (size_t)(mg * 32 + 16 + lr) * 1024;
        #pragma unroll
        for (int ch = 0; ch < 4; ++ch) {
          const int kcA = kq * 8 + ch * 2;
          const int kkA = kcA * 32 + lg * 8;
          const int kkB = kkA + 32;
          uint4 q0, q1, q2, q3, q4, q5, q6, q7;
          coh_load8(s0 + kkA, s0 + kkA + 4, s1 + kkA, s1 + kkA + 4,
                    s0 + kkB, s0 + kkB + 4, s1 + kkB, s1 + kkB + 4,
                    q0, q1, q2, q3, q4, q5, q6, q7);
          #pragma unroll
          for (int s = 0; s < 2; ++s) {
            const int kc = kcA + s;
            half8 hi[2], lo[2];
            unpack8(s ? q4 : q0, s ? q5 : q1, hi[0], lo[0]);
            unpack8(s ? q6 : q2, s ? q7 : q3, hi[1], lo[1]);
            #pragma unroll
            for (int g = 0; g < 3; ++g) {
              const half8 bf = *(const half8*)(wtile + ((size_t)(g * 32 + kc) * 64 + l64) * 8);
              acc[g][0] = __builtin_amdgcn_mfma_f32_16x16x32_f16(hi[0], bf, acc[g][0], 0, 0, 0);
              acc[g][1] = __builtin_amdgcn_mfma_f32_16x16x32_f16(hi[1], bf, acc[g][1], 0, 0, 0);
              acc[g][0] = __builtin_amdgcn_mfma_f32_16x16x32_f16(lo[0], bf, acc[g][0], 0, 0, 0);
              acc[g][1] = __builtin_amdgcn_mfma_f32_16x16x32_f16(lo[1], bf, acc[g][1], 0, 0, 0);
            }
          }
        }
      }

      // ---- reduce kq partials ----
      #pragma unroll
      for (int g = 0; g < 3; ++g)
        #pragma unroll
        for (int mt = 0; mt < 2; ++mt)
          #pragma unroll
          for (int pp = 0; pp < 4; ++pp)
            pre[(((kq * 3 + g) * 64) + (mg * 2 + mt) * 16 + lg * 4 + pp) * 16 + lr] =
                acc[g][mt][pp];
      __syncthreads();

      // ---- pointwise LSTM update ----
      uint32_t* hdst = hrec_arr + ((size_t)(d * 2 + par) << 16);
      #pragma unroll
      for (int rep = 0; rep < 2; ++rep) {
        const int e = tid + rep * 512;
        const int r = e >> 4, jj = e & 15;
        const int jg = j0 + jj;
        float fp = p.bias[d][0][l * E_SZ + jg];
        float ip = p.bias[d][1][l * E_SZ + jg];
        float cp = p.bias[d][2][l * E_SZ + jg];
        #pragma unroll
        for (int k = 0; k < 4; ++k) {
          fp += pre[((k * 3 + 0) * 64 + r) * 16 + jj];
          ip += pre[((k * 3 + 1) * 64 + r) * 16 + jj];
          cp += pre[((k * 3 + 2) * 64 + r) * 16 + jj];
        }
        const float fg = 1.f / (1.f + expf(-fp));
        const float ig = 1.f / (1.f + expf(-ip));
        const float gg = tanhf(cp);
        const float cold = cst[(size_t)r * 1024 + jg];
        const float cnew = cold * fg + ig * gg;
        const float hnew = tanhf(cnew) * fg;   // forget gate reused as output gate
        cst[(size_t)r * 1024 + jg] = cnew;     // c is block-private: plain cached
        // h crosses XCDs: write-through to coherence point, no fences
        __hip_atomic_store(&hdst[(size_t)r * 1024 + jg], pack_split(hnew),
                           __ATOMIC_RELAXED, __HIP_MEMORY_SCOPE_AGENT);
        if (l) wred[r * 16 + jj] = hnew * p.wordW[d * E_SZ + jg];
      }
      if (l) {
        __syncthreads();
        if (tid < 64) {
          float s = 0.f;
          #pragma unroll
          for (int q = 0; q < 16; ++q) s += wred[tid * 16 + q];
          p.wpart[((size_t)(d * 64 + j16) * S_LEN + td) * 64 + tid] = s;
        }
      }
    }

    // ---- per-direction device barrier: all RELAXED (no L2 inv/wb) ----
    __syncthreads();   // each wave drains vmcnt here -> h stores at coherence pt
    if (idx == 0) {
      if (tid >= 1 && tid < 128) {
        int f, it = 0;
        do {
          f = __hip_atomic_load(p.flags + (d * 128 + tid) * 16,
                                __ATOMIC_RELAXED, __HIP_MEMORY_SCOPE_AGENT);
          if (f >= ph + 1) break;
          __builtin_amdgcn_s_sleep(1);
        } while (++it < (1 << 22));
      }
      __builtin_amdgcn_fence(__ATOMIC_ACQUIRE, "workgroup");  // compiler ordering only
      __syncthreads();
      if (tid == 0) {
        asm volatile("s_waitcnt vmcnt(0)" ::: "memory");
        __hip_atomic_store(p.rel + d * 16, ph + 1, __ATOMIC_RELAXED,
                           __HIP_MEMORY_SCOPE_AGENT);
      }
    } else {
      if (tid == 0) {
        asm volatile("s_waitcnt vmcnt(0)" ::: "memory");
        __hip_atomic_store(p.flags + (d * 128 + idx) * 16, ph + 1,
                           __ATOMIC_RELAXED, __HIP_MEMORY_SCOPE_AGENT);
        int f, it = 0;
        do {
          f = __hip_atomic_load(p.rel + d * 16, __ATOMIC_RELAXED,
                                __HIP_MEMORY_SCOPE_AGENT);
          if (f >= ph + 1) break;
          __builtin_amdgcn_s_sleep(1);
        } while (++it < (1 << 22));
      }
      __builtin_amdgcn_fence(__ATOMIC_ACQUIRE, "workgroup");  // compiler ordering only
    }
    __syncthreads();
  }
}

// w[b][t] = word_b + sum over (d,j16) of wpart
__global__ __launch_bounds__(64)
void reduce_w_kernel(const float* wpart, const float* wordb, float* w) {
  const int t = blockIdx.x, b = threadIdx.x;
  float s = wordb[0];
  #pragma unroll 8
  for (int q = 0; q < 128; ++q)
    s += wpart[((size_t)q * S_LEN + t) * 64 + b];
  w[b * S_LEN + t] = s;
}

__global__ __launch_bounds__(320)
void final_kernel(const float* w, const float* predW, const float* predb, float* out) {
  const int tid = threadIdx.x;
  if (tid >= B_SZ * NLBL) return;
  const int b = tid / NLBL, lab = tid % NLBL;
  float s = predb[lab];
  #pragma unroll 8
  for (int t = 0; t < S_LEN; ++t) s += w[b * S_LEN + t] * predW[t * NLBL + lab];
  out[tid] = s;
}

// ================= fallback path (proven round-2 kernels) =================
#define KC    128
#define NC    16
#define BKP   136
#define OFF_H0 0
#define OFF_H1 262144
#define OFF_C0 524288
#define OFF_C1 655360
#define OFF_W  786432
#define WS_TOTAL 794624

struct ParamsFB {
  const float* x;
  const float* W[2][3];
  const float* bias[2][3];
  const float* wordW;
  float* h0;
  float* h1;
  float* c0;
  float* c1;
  float* w;
};

__global__ __launch_bounds__(256)
void init_fb(float* ws, const float* hs, const float* cs, const float* wordb) {
  size_t i = (size_t)blockIdx.x * 256 + threadIdx.x;
  if (i < OFF_C0) {
    size_t be = i & (size_t)(B_SZ * E_SZ - 1);
    ws[i] = hs[be];
  } else if (i < OFF_W) {
    size_t be = (i - OFF_C0) & (size_t)(B_SZ * E_SZ - 1);
    ws[i] = cs[be];
  } else if (i < WS_TOTAL) {
    ws[i] = wordb[0];
  }
}

template<int LAYER>
__global__ __launch_bounds__(512)
void step_fb(ParamsFB p, int t) {
  __shared__ __align__(16) unsigned char lds_raw[53248];
  _Float16* BtBase = (_Float16*)lds_raw;
  float* pre = (float*)lds_raw;
  float* wcs = (float*)(lds_raw + 49152);

  const int tid = threadIdx.x;
  const int l = tid & 63;
  const int lr = l & 15;
  const int lg = l >> 4;
  const int wv = tid >> 6;
  const int kq = wv & 3;
  const int mg = wv >> 2;

  const int blk = blockIdx.x;
  const int jg = blk & 63;
  const int d = blk >> 6;
  const int j0 = jg * 16;
  const int td = d ? (S_LEN - 1 - t) : t;
  const int cur = t & 1, nxt = cur ^ 1;

  const float* hsrc = (LAYER == 0 ? p.h0 : p.h1) + (size_t)(d * 2 + cur) * (B_SZ * E_SZ);
  const float* isrc = (LAYER == 0) ? p.x : p.h0 + (size_t)(d * 2 + nxt) * (B_SZ * E_SZ);
  const float* Wg0 = p.W[d][0] + (size_t)LAYER * 2 * E_SZ * E_SZ;
  const float* Wg1 = p.W[d][1] + (size_t)LAYER * 2 * E_SZ * E_SZ;
  const float* Wg2 = p.W[d][2] + (size_t)LAYER * 2 * E_SZ * E_SZ;

  auto loadA = [&](int c, float4 dst[2][2]) {
    const int kk = c * KC + kq * 32 + lg * 8;
    #pragma unroll
    for (int mi = 0; mi < 2; ++mi) {
      const int row = (mg * 2 + mi) * 16 + lr;
      const float* ptr;
      if (kk < E_SZ) ptr = hsrc + (size_t)row * E_SZ + kk;
      else if (LAYER == 0) ptr = isrc + ((size_t)row * S_LEN + td) * E_SZ + (kk - E_SZ);
      else ptr = isrc + (size_t)row * E_SZ + (kk - E_SZ);
      dst[mi][0] = *(const float4*)ptr;
      dst[mi][1] = *(const float4*)(ptr + 4);
    }
  };
  auto loadB = [&](int c, float4 breg[3]) {
    #pragma unroll
    for (int it = 0; it < 3; ++it) {
      const int idx2 = tid + it * 512;
      const int row = idx2 >> 2;
      const int g = row >> 7;
      const int kk = row & 127;
      const int q = idx2 & 3;
      const float* W = (g == 0 ? Wg0 : (g == 1 ? Wg1 : Wg2));
      breg[it] = *(const float4*)(W + (size_t)(c * KC + kk) * E_SZ + j0 + q * 4);
    }
  };
  auto writeB = [&](const float4 breg[3], int buf) {
    _Float16* Bt = BtBase + buf * (48 * BKP);
    #pragma unroll
    for (int it = 0; it < 3; ++it) {
      const int idx2 = tid + it * 512;
      const int row = idx2 >> 2;
      const int g = row >> 7;
      const int kk = row & 127;
      const int q = idx2 & 3;
      #pragma unroll
      for (int jj = 0; jj < 4; ++jj)
        Bt[(g * 16 + q * 4 + jj) * BKP + kk] = (_Float16)breg[it][jj];
    }
  };

  float4 aCur[2][2], aNxt[2][2];
  float4 breg[3];
  loadB(0, breg);
  loadA(0, aCur);
  writeB(breg, 0);
  __syncthreads();

  const f32x4 zero = {0.f, 0.f, 0.f, 0.f};
  f32x4 acc[3][2];
  #pragma unroll
  for (int g = 0; g < 3; ++g) { acc[g][0] = zero; acc[g][1] = zero; }

  #pragma unroll
  for (int c = 0; c < NC; ++c) {
    half8 a1[2], a2[2];
    #pragma unroll
    for (int mi = 0; mi < 2; ++mi) {
      #pragma unroll
      for (int i = 0; i < 8; ++i) {
        const float v = (i < 4) ? aCur[mi][0][i] : aCur[mi][1][i - 4];
        const _Float16 h = (_Float16)v;
        a1[mi][i] = h;
        a2[mi][i] = (_Float16)(v - (float)h);
      }
    }
    if (c + 1 < NC) { loadB(c + 1, breg); loadA(c + 1, aNxt); }

    const _Float16* BtR = BtBase + (c & 1) * (48 * BKP) + kq * 32 + lg * 8;
    half8 bf[3];
    #pragma unroll
    for (int g = 0; g < 3; ++g)
      bf[g] = *(const half8*)(BtR + (g * 16 + lr) * BKP);

    #pragma unroll
    for (int g = 0; g < 3; ++g) {
      acc[g][0] = __builtin_amdgcn_mfma_f32_16x16x32_f16(a1[0], bf[g], acc[g][0], 0, 0, 0);
      acc[g][1] = __builtin_amdgcn_mfma_f32_16x16x32_f16(a1[1], bf[g], acc[g][1], 0, 0, 0);
    }
    #pragma unroll
    for (int g = 0; g < 3; ++g) {
      acc[g][0] = __builtin_amdgcn_mfma_f32_16x16x32_f16(a2[0], bf[g], acc[g][0], 0, 0, 0);
      acc[g][1] = __builtin_amdgcn_mfma_f32_16x16x32_f16(a2[1], bf[g], acc[g][1], 0, 0, 0);
    }

    if (c + 1 < NC) {
      writeB(breg, (c + 1) & 1);
      __syncthreads();
      #pragma unroll
      for (int mi = 0; mi < 2; ++mi) {
        aCur[mi][0] = aNxt[mi][0];
        aCur[mi][1] = aNxt[mi][1];
      }
    }
  }

  __syncthreads();
  #pragma unroll
  for (int g = 0; g < 3; ++g)
    #pragma unroll
    for (int mi = 0; mi < 2; ++mi)
      #pragma unroll
      for (int pp = 0; pp < 4; ++pp)
        pre[(((kq * 3 + g) * 64) + (mg * 2 + mi) * 16 + lg * 4 + pp) * 16 + lr] =
            acc[g][mi][pp];
  __syncthreads();

  float* cstf = (LAYER == 0 ? p.c0 : p.c1) + (size_t)d * (B_SZ * E_SZ);
  float* hdst = (LAYER == 0 ? p.h0 : p.h1) + (size_t)(d * 2 + nxt) * (B_SZ * E_SZ);

  #pragma unroll
  for (int rep = 0; rep < 2; ++rep) {
    const int e = tid + rep * 512;
    const int r = e >> 4;
    const int j = e & 15;
    const int jglob = j0 + j;
    float fp = p.bias[d][0][LAYER * E_SZ + jglob];
    float ip = p.bias[d][1][LAYER * E_SZ + jglob];
    float cp = p.bias[d][2][LAYER * E_SZ + jglob];
    #pragma unroll
    for (int k = 0; k < 4; ++k) {
      fp += pre[((k * 3 + 0) * 64 + r) * 16 + j];
      ip += pre[((k * 3 + 1) * 64 + r) * 16 + j];
      cp += pre[((k * 3 + 2) * 64 + r) * 16 + j];
    }
    const float fg = 1.f / (1.f + expf(-fp));
    const float ig = 1.f / (1.f + expf(-ip));
    const float gg = tanhf(cp);
    const float cold = cstf[(size_t)r * E_SZ + jglob];
    const float cnew = cold * fg + ig * gg;
    const float hnew = tanhf(cnew) * fg;
    cstf[(size_t)r * E_SZ + jglob] = cnew;
    hdst[(size_t)r * E_SZ + jglob] = hnew;
    if (LAYER == 1) wcs[r * 16 + j] = hnew * p.wordW[(size_t)d * E_SZ + jglob];
  }

  if (LAYER == 1) {
    __syncthreads();
    if (tid < 64) {
      float s = 0.f;
      #pragma unroll
      for (int q = 0; q < 16; ++q) s += wcs[tid * 16 + q];
      atomicAdd(&p.w[(size_t)tid * S_LEN + td], s);
    }
  }
}

// ================= launcher =================
extern "C" void kernel_launch(void* const* d_in, const int* in_sizes, int n_in,
                              void* d_out, int out_size, void* d_ws, size_t ws_size,
                              hipStream_t stream) {
  char* ws = (char*)d_ws;

  if (ws_size >= WS_NEED) {
    PP p;
    p.x = (const float*)d_in[0];
    p.W[0][0] = (const float*)d_in[5];  p.bias[0][0] = (const float*)d_in[6];
    p.W[0][1] = (const float*)d_in[7];  p.bias[0][1] = (const float*)d_in[8];
    p.W[0][2] = (const float*)d_in[9];  p.bias[0][2] = (const float*)d_in[10];
    p.W[1][0] = (const float*)d_in[11]; p.bias[1][0] = (const float*)d_in[12];
    p.W[1][1] = (const float*)d_in[13]; p.bias[1][1] = (const float*)d_in[14];
    p.W[1][2] = (const float*)d_in[15]; p.bias[1][2] = (const float*)d_in[16];
    p.wordW = (const float*)d_in[17];
    p.wrec  = (_Float16*)(ws + WOFF_WREC);
    p.winp  = (_Float16*)(ws + WOFF_WINP);
    p.x16   = (_Float16*)(ws + WOFF_X16);
    p.h0    = (uint32_t*)(ws + WOFF_H0);
    p.h1    = (uint32_t*)(ws + WOFF_H1);
    p.c     = (float*)(ws + WOFF_C);
    p.w     = (float*)(ws + WOFF_W);
    p.wpart = (float*)(ws + WOFF_WPART);
    p.flags = (int*)(ws + WOFF_FLAGS);
    p.rel   = (int*)(ws + WOFF_FLAGS) + 2 * 128 * 16;

    hipFuncSetAttribute((const void*)lstm_persist,
                        hipFuncAttributeMaxDynamicSharedMemorySize, 151552);

    conv_w_kernel<<<1536, 256, 0, stream>>>(p);
    conv_x_kernel<<<4096, 256, 0, stream>>>(p.x, p.x16);
    init2_kernel<<<(INIT_TOTAL + 255) / 256, 256, 0, stream>>>(
        p, (const float*)d_in[2], (const float*)d_in[1]);
    lstm_persist<<<256, 512, 151552, stream>>>(p);
    reduce_w_kernel<<<128, 64, 0, stream>>>(p.wpart, (const float*)d_in[18], p.w);
    final_kernel<<<1, 320, 0, stream>>>(p.w, (const float*)d_in[19],
                                        (const float*)d_in[20], (float*)d_out);
  } else {
    float* wsf = (float*)d_ws;
    ParamsFB p;
    p.x = (const float*)d_in[0];
    p.W[0][0] = (const float*)d_in[5];  p.bias[0][0] = (const float*)d_in[6];
    p.W[0][1] = (const float*)d_in[7];  p.bias[0][1] = (const float*)d_in[8];
    p.W[0][2] = (const float*)d_in[9];  p.bias[0][2] = (const float*)d_in[10];
    p.W[1][0] = (const float*)d_in[11]; p.bias[1][0] = (const float*)d_in[12];
    p.W[1][1] = (const float*)d_in[13]; p.bias[1][1] = (const float*)d_in[14];
    p.W[1][2] = (const float*)d_in[15]; p.bias[1][2] = (const float*)d_in[16];
    p.wordW = (const float*)d_in[17];
    p.h0 = wsf + OFF_H0;
    p.h1 = wsf + OFF_H1;
    p.c0 = wsf + OFF_C0;
    p.c1 = wsf + OFF_C1;
    p.w  = wsf + OFF_W;

    init_fb<<<WS_TOTAL / 256, 256, 0, stream>>>(
        wsf, (const float*)d_in[2], (const float*)d_in[1], (const float*)d_in[18]);
    for (int t = 0; t < S_LEN; ++t) {
      step_fb<0><<<128, 512, 0, stream>>>(p, t);
      step_fb<1><<<128, 512, 0, stream>>>(p, t);
    }
    final_kernel<<<1, 320, 0, stream>>>(p.w, (const float*)d_in[19],
                                        (const float*)d_in[20], (float*)d_out);
  }
}

// Round 8
// 1992.622 us; speedup vs baseline: 11.3807x; 1.3636x over previous
//
#include <hip/hip_runtime.h>
#include <cstddef>
#include <cstdint>

typedef _Float16 half8 __attribute__((ext_vector_type(8)));
typedef float f32x4 __attribute__((ext_vector_type(4)));

#define S_LEN 128
#define B_SZ  64
#define E_SZ  1024
#define NLBL  5
#define NPHASE 129

// ---------------- new-path ws layout (bytes) ----------------
#define WOFF_WREC  0ull
#define WOFF_WINP  25165824ull
#define WOFF_X16   50331648ull
#define WOFF_H0    67108864ull
#define WOFF_H1    68157440ull
#define WOFF_H0F   69206016ull
#define WOFF_W     69730304ull
#define WOFF_WPART 69763072ull
#define WOFF_FLAGS 73957376ull
#define WS_NEED    73973888ull

// init elements: h0 262144 + h1 262144 + h0f 131072 + flags 4128
#define INIT_TOTAL 659488

struct PP {
  const float* x;
  const float* W[2][3];
  const float* bias[2][3];
  const float* wordW;
  const float* cs0;
  _Float16* wrec;   // [ (d*2+l)*64 + j16 ][ g*16384 + (kc*64+lane)*8 + e ] f16
  _Float16* winp;
  _Float16* x16;    // [B][S][E] f16
  uint32_t* h0;     // [2d][2par][64][1024] packed (hi f16 low, lo f16 high)
  uint32_t* h1;
  uint32_t* h0f;    // [2d][2par][64][512] 2xf16 (layer-0 h, single precision copy)
  float* w;         // [64][128]
  float* wpart;     // [2d][64 j16][128 t][64 b]
  int* flags;       // [2d][128] stride-16 ints
};

__device__ __forceinline__ uint32_t pack_split(float v) {
  _Float16 h = (_Float16)v;
  _Float16 l2 = (_Float16)(v - (float)h);
  return (uint32_t)__builtin_bit_cast(unsigned short, h) |
         ((uint32_t)__builtin_bit_cast(unsigned short, l2) << 16);
}

__device__ __forceinline__ void unpack8(uint4 a, uint4 b, half8& hi, half8& lo) {
  uint32_t v[8] = {a.x, a.y, a.z, a.w, b.x, b.y, b.z, b.w};
  #pragma unroll
  for (int i = 0; i < 8; ++i) {
    hi[i] = __builtin_bit_cast(_Float16, (unsigned short)(v[i] & 0xffffu));
    lo[i] = __builtin_bit_cast(_Float16, (unsigned short)(v[i] >> 16));
  }
}

#define MFMA16(A, B, C) __builtin_amdgcn_mfma_f32_16x16x32_f16(A, B, C, 0, 0, 0)

// ---- issue asm primitives (outputs only -> no tied operands) ----
#define S_ISSUE_H8(Q, P0, P1, P2, P3, P4, P5, P6, P7)                      \
  asm volatile("global_load_dwordx4 %0, %8, off sc0 sc1\n\t"               \
               "global_load_dwordx4 %1, %9, off sc0 sc1\n\t"               \
               "global_load_dwordx4 %2, %10, off sc0 sc1\n\t"              \
               "global_load_dwordx4 %3, %11, off sc0 sc1\n\t"              \
               "global_load_dwordx4 %4, %12, off sc0 sc1\n\t"              \
               "global_load_dwordx4 %5, %13, off sc0 sc1\n\t"              \
               "global_load_dwordx4 %6, %14, off sc0 sc1\n\t"              \
               "global_load_dwordx4 %7, %15, off sc0 sc1"                  \
               : "=&v"((Q)[0]), "=&v"((Q)[1]), "=&v"((Q)[2]), "=&v"((Q)[3]), \
                 "=&v"((Q)[4]), "=&v"((Q)[5]), "=&v"((Q)[6]), "=&v"((Q)[7]) \
               : "v"(P0), "v"(P1), "v"(P2), "v"(P3), "v"(P4), "v"(P5),     \
                 "v"(P6), "v"(P7))

#define S_ISSUE_A4C(Q, P0, P1, P2, P3)                                     \
  asm volatile("global_load_dwordx4 %0, %4, off sc0 sc1\n\t"               \
               "global_load_dwordx4 %1, %5, off sc0 sc1\n\t"               \
               "global_load_dwordx4 %2, %6, off sc0 sc1\n\t"               \
               "global_load_dwordx4 %3, %7, off sc0 sc1"                   \
               : "=&v"((Q)[0]), "=&v"((Q)[1]), "=&v"((Q)[2]), "=&v"((Q)[3]) \
               : "v"(P0), "v"(P1), "v"(P2), "v"(P3))

#define S_ISSUE_A4P(Q, P0, P1, P2, P3)                                     \
  asm volatile("global_load_dwordx4 %0, %4, off\n\t"                       \
               "global_load_dwordx4 %1, %5, off\n\t"                       \
               "global_load_dwordx4 %2, %6, off\n\t"                       \
               "global_load_dwordx4 %3, %7, off"                           \
               : "=&v"((Q)[0]), "=&v"((Q)[1]), "=&v"((Q)[2]), "=&v"((Q)[3]) \
               : "v"(P0), "v"(P1), "v"(P2), "v"(P3))

#define S_ISSUE_W6(Q, P0, P1, P2, P3, P4, P5)                              \
  asm volatile("global_load_dwordx4 %0, %6, off\n\t"                       \
               "global_load_dwordx4 %1, %7, off\n\t"                       \
               "global_load_dwordx4 %2, %8, off\n\t"                       \
               "global_load_dwordx4 %3, %9, off\n\t"                       \
               "global_load_dwordx4 %4, %10, off\n\t"                      \
               "global_load_dwordx4 %5, %11, off"                          \
               : "=&v"((Q)[0]), "=&v"((Q)[1]), "=&v"((Q)[2]), "=&v"((Q)[3]), \
                 "=&v"((Q)[4]), "=&v"((Q)[5])                              \
               : "v"(P0), "v"(P1), "v"(P2), "v"(P3), "v"(P4), "v"(P5))

// counted wait: bare asm + sched_barrier fence (rule-18 pattern; no tied ops)
#define S_WAITV(N)                                                         \
  asm volatile("s_waitcnt vmcnt(" #N ")" ::: "memory");                    \
  __builtin_amdgcn_sched_barrier(0)

__device__ __forceinline__ void comp_rec2(const uint4* q, int kcA,
                                          const _Float16* wlds, int l64,
                                          f32x4 acc[3][2]) {
  #pragma unroll
  for (int s = 0; s < 2; ++s) {
    const int kc = kcA + s;
    half8 hi0, lo0, hi1, lo1;
    unpack8(q[s * 4 + 0], q[s * 4 + 1], hi0, lo0);
    unpack8(q[s * 4 + 2], q[s * 4 + 3], hi1, lo1);
    #pragma unroll
    for (int g = 0; g < 3; ++g) {
      const half8 bf = *(const half8*)(wlds + ((size_t)(g * 32 + kc) * 64 + l64) * 8);
      acc[g][0] = MFMA16(hi0, bf, acc[g][0]);
      acc[g][1] = MFMA16(hi1, bf, acc[g][1]);
      acc[g][0] = MFMA16(lo0, bf, acc[g][0]);
      acc[g][1] = MFMA16(lo1, bf, acc[g][1]);
    }
  }
}

__device__ __forceinline__ void comp_inp2(const uint4* aq, const uint4* wq,
                                          f32x4 acc[3][2]) {
  #pragma unroll
  for (int s = 0; s < 2; ++s) {
    const half8 a0 = __builtin_bit_cast(half8, aq[s * 2 + 0]);
    const half8 a1 = __builtin_bit_cast(half8, aq[s * 2 + 1]);
    #pragma unroll
    for (int g = 0; g < 3; ++g) {
      const half8 bf = __builtin_bit_cast(half8, wq[s * 3 + g]);
      acc[g][0] = MFMA16(a0, bf, acc[g][0]);
      acc[g][1] = MFMA16(a1, bf, acc[g][1]);
    }
  }
}

// -------- conversion kernels (run every launch; deterministic) --------
__global__ __launch_bounds__(256)
void conv_w_kernel(PP p) {
  const int blk = blockIdx.x;           // (((d*2+l)*3+g)*64 + j16)*2 + part
  const int part = blk & 1;
  const int j16 = (blk >> 1) & 63;
  const int rest = blk >> 7;
  const int g = rest % 3;
  const int dl = rest / 3;
  const int l = dl & 1, d = dl >> 1;
  const int tid = threadIdx.x;
  const int l2 = tid & 63, kc0 = tid >> 6;
  const float* W = p.W[d][g] + (size_t)l * 2048 * 1024 + (size_t)(part ? 1024 : 0) * 1024;
  _Float16* out = (part ? p.winp : p.wrec) + (size_t)(dl * 64 + j16) * 49152 + (size_t)g * 16384;
  const int j = j16 * 16 + (l2 & 15);
  const int kbase = (l2 >> 4) * 8;
  #pragma unroll
  for (int ki = 0; ki < 8; ++ki) {
    const int kc = kc0 * 8 + ki;
    const int k0 = kc * 32 + kbase;
    half8 h;
    #pragma unroll
    for (int e2 = 0; e2 < 8; ++e2) h[e2] = (_Float16)W[(size_t)(k0 + e2) * 1024 + j];
    *(half8*)(out + ((size_t)kc * 64 + l2) * 8) = h;
  }
}

__global__ __launch_bounds__(256)
void conv_x_kernel(const float* x, _Float16* x16) {
  const size_t i8 = ((size_t)blockIdx.x * 256 + threadIdx.x) * 8;
  float4 a = *(const float4*)(x + i8);
  float4 b = *(const float4*)(x + i8 + 4);
  half8 h;
  h[0] = (_Float16)a.x; h[1] = (_Float16)a.y; h[2] = (_Float16)a.z; h[3] = (_Float16)a.w;
  h[4] = (_Float16)b.x; h[5] = (_Float16)b.y; h[6] = (_Float16)b.z; h[7] = (_Float16)b.w;
  *(half8*)(x16 + i8) = h;
}

__global__ __launch_bounds__(256)
void init2_kernel(PP p, const float* hs) {
  const size_t i = (size_t)blockIdx.x * 256 + threadIdx.x;
  if (i < 262144) {
    p.h0[i] = pack_split(hs[i & 65535]);
  } else if (i < 524288) {
    p.h1[i - 262144] = pack_split(hs[i & 65535]);
  } else if (i < 655360) {
    const size_t ip = i - 524288;       // [2][2][64][512]
    const size_t be = ip & 32767;
    const size_t b = be >> 9, ep = be & 511;
    const _Float16 v0 = (_Float16)hs[b * 1024 + ep * 2];
    const _Float16 v1 = (_Float16)hs[b * 1024 + ep * 2 + 1];
    p.h0f[ip] = (uint32_t)__builtin_bit_cast(unsigned short, v0) |
                ((uint32_t)__builtin_bit_cast(unsigned short, v1) << 16);
  } else if (i < INIT_TOTAL) {
    p.flags[i - 655360] = 0;
  }
}

// ---------------- persistent bidirectional LSTM ----------------
__global__ __launch_bounds__(512, 2)
void lstm_persist(PP p) {
  extern __shared__ char smem[];
  _Float16* wlds = (_Float16*)smem;            // 98304 B: rec weights
  float* pre  = (float*)(smem + 98304);        // 49152 B: kq partials
  float* wred = (float*)(smem + 147456);       // 4096 B: word-proj scratch

  const int tid = threadIdx.x;
  const int l64 = tid & 63, lr = l64 & 15, lg = l64 >> 4;
  const int wv = tid >> 6, kq = wv & 3, mg = wv >> 2;
  const int blk = blockIdx.x;
  const int j16 = blk & 63, l = (blk >> 6) & 1, d = blk >> 7;
  const int idx = blk & 127;
  const int j0 = j16 * 16;

  const size_t tileoff = (size_t)((d * 2 + l) * 64 + j16) * 49152;
  {
    const float4* src = (const float4*)(p.wrec + tileoff);
    float4* dst = (float4*)wlds;
    #pragma unroll
    for (int i = 0; i < 12; ++i) dst[tid + i * 512] = src[tid + i * 512];
  }
  const _Float16* wtile = p.winp + tileoff;
  uint32_t* hrec_arr = l ? p.h1 : p.h0;

  // ---- prologue hoists: bias / wordW / c-state live in registers ----
  const int pr = tid >> 3;          // pointwise row 0..63
  const int pj = (tid & 7) * 2;     // pointwise col pair
  const int pjg = j0 + pj;
  const float bsf0 = p.bias[d][0][l * E_SZ + pjg], bsf1 = p.bias[d][0][l * E_SZ + pjg + 1];
  const float bsi0 = p.bias[d][1][l * E_SZ + pjg], bsi1 = p.bias[d][1][l * E_SZ + pjg + 1];
  const float bsc0 = p.bias[d][2][l * E_SZ + pjg], bsc1 = p.bias[d][2][l * E_SZ + pjg + 1];
  const float ww0 = p.wordW[d * E_SZ + pjg], ww1 = p.wordW[d * E_SZ + pjg + 1];
  float creg0 = p.cs0[(size_t)pr * E_SZ + pjg];
  float creg1 = p.cs0[(size_t)pr * E_SZ + pjg + 1];
  __syncthreads();

  for (int ph = 0; ph < NPHASE; ++ph) {
    const int t = l ? (ph - 1) : ph;
    if ((unsigned)t < (unsigned)S_LEN) {
      const int par = t & 1, prev = par ^ 1;
      const int td = d ? (S_LEN - 1 - t) : t;
      const uint32_t* hA = hrec_arr + ((size_t)(d * 2 + prev) << 16);
      const uint32_t* r0 = hA + (size_t)(mg * 32 + lr) * 1024;
      const uint32_t* r1 = hA + (size_t)(mg * 32 + 16 + lr) * 1024;
      // input-half A sources
      const _Float16* a0base;
      const _Float16* a1base;
      if (l == 0) {
        a0base = p.x16 + ((size_t)(mg * 32 + lr) * S_LEN + td) * 1024;
        a1base = p.x16 + ((size_t)(mg * 32 + 16 + lr) * S_LEN + td) * 1024;
      } else {
        const _Float16* hf = (const _Float16*)(p.h0f + ((size_t)(d * 2 + par) << 15));
        a0base = hf + (size_t)(mg * 32 + lr) * 1024;
        a1base = hf + (size_t)(mg * 32 + 16 + lr) * 1024;
      }

      const f32x4 zero = {0.f, 0.f, 0.f, 0.f};
      f32x4 acc[3][2];
      #pragma unroll
      for (int g = 0; g < 3; ++g) { acc[g][0] = zero; acc[g][1] = zero; }

      auto issue_rec = [&](int c, uint4* Q) {
        const int kkA = (kq * 8 + c * 2) * 32 + lg * 8;
        S_ISSUE_H8(Q, r0 + kkA, r0 + kkA + 4, r1 + kkA, r1 + kkA + 4,
                   r0 + kkA + 32, r0 + kkA + 36, r1 + kkA + 32, r1 + kkA + 36);
      };
      auto issue_a = [&](int i, uint4* Q) {
        const int kk = (kq * 8 + i * 2) * 32 + lg * 8;
        if (l == 0) {
          S_ISSUE_A4P(Q, a0base + kk, a1base + kk, a0base + kk + 32, a1base + kk + 32);
        } else {
          S_ISSUE_A4C(Q, a0base + kk, a1base + kk, a0base + kk + 32, a1base + kk + 32);
        }
      };
      auto issue_w = [&](int i, uint4* Q) {
        const int kc0 = kq * 8 + i * 2;
        S_ISSUE_W6(Q,
                   wtile + ((size_t)(0 * 32 + kc0) * 64 + l64) * 8,
                   wtile + ((size_t)(1 * 32 + kc0) * 64 + l64) * 8,
                   wtile + ((size_t)(2 * 32 + kc0) * 64 + l64) * 8,
                   wtile + ((size_t)(0 * 32 + kc0 + 1) * 64 + l64) * 8,
                   wtile + ((size_t)(1 * 32 + kc0 + 1) * 64 + l64) * 8,
                   wtile + ((size_t)(2 * 32 + kc0 + 1) * 64 + l64) * 8);
      };

      uint4 hq[2][8], aq2[2][4], wq2[2][6];
      // ---- depth-1 pipelined chunk schedule (counted vmcnt) ----
      issue_rec(0, hq[0]);
      issue_rec(1, hq[1]); S_WAITV(8);   comp_rec2(hq[0], kq * 8 + 0, wlds, l64, acc);
      issue_rec(2, hq[0]); S_WAITV(8);   comp_rec2(hq[1], kq * 8 + 2, wlds, l64, acc);
      issue_rec(3, hq[1]); S_WAITV(8);   comp_rec2(hq[0], kq * 8 + 4, wlds, l64, acc);
      issue_a(0, aq2[0]); issue_w(0, wq2[0]);
      S_WAITV(10);                       comp_rec2(hq[1], kq * 8 + 6, wlds, l64, acc);
      issue_a(1, aq2[1]); issue_w(1, wq2[1]);
      S_WAITV(10);                       comp_inp2(aq2[0], wq2[0], acc);
      issue_a(2, aq2[0]); issue_w(2, wq2[0]);
      S_WAITV(10);                       comp_inp2(aq2[1], wq2[1], acc);
      issue_a(3, aq2[1]); issue_w(3, wq2[1]);
      S_WAITV(10);                       comp_inp2(aq2[0], wq2[0], acc);
      S_WAITV(0);                        comp_inp2(aq2[1], wq2[1], acc);

      // ---- reduce kq partials ----
      #pragma unroll
      for (int g = 0; g < 3; ++g)
        #pragma unroll
        for (int mt = 0; mt < 2; ++mt)
          #pragma unroll
          for (int pp = 0; pp < 4; ++pp)
            pre[(((kq * 3 + g) * 64) + (mg * 2 + mt) * 16 + lg * 4 + pp) * 16 + lr] =
                acc[g][mt][pp];
      __syncthreads();

      // ---- pointwise LSTM update (1 row x 2 cols per thread) ----
      float fp0 = bsf0, fp1 = bsf1, ip0 = bsi0, ip1 = bsi1, cp0 = bsc0, cp1 = bsc1;
      #pragma unroll
      for (int k = 0; k < 4; ++k) {
        fp0 += pre[((k * 3 + 0) * 64 + pr) * 16 + pj];
        fp1 += pre[((k * 3 + 0) * 64 + pr) * 16 + pj + 1];
        ip0 += pre[((k * 3 + 1) * 64 + pr) * 16 + pj];
        ip1 += pre[((k * 3 + 1) * 64 + pr) * 16 + pj + 1];
        cp0 += pre[((k * 3 + 2) * 64 + pr) * 16 + pj];
        cp1 += pre[((k * 3 + 2) * 64 + pr) * 16 + pj + 1];
      }
      const float fg0 = 1.f / (1.f + expf(-fp0)), fg1 = 1.f / (1.f + expf(-fp1));
      const float ig0 = 1.f / (1.f + expf(-ip0)), ig1 = 1.f / (1.f + expf(-ip1));
      const float gg0 = tanhf(cp0), gg1 = tanhf(cp1);
      creg0 = creg0 * fg0 + ig0 * gg0;
      creg1 = creg1 * fg1 + ig1 * gg1;
      const float h0v = tanhf(creg0) * fg0;    // forget gate reused as output gate
      const float h1v = tanhf(creg1) * fg1;

      uint32_t* hdst = hrec_arr + ((size_t)(d * 2 + par) << 16) + (size_t)pr * 1024 + pjg;
      const unsigned long long pk =
          (unsigned long long)pack_split(h0v) | ((unsigned long long)pack_split(h1v) << 32);
      asm volatile("global_store_dwordx2 %0, %1, off sc0 sc1" ::"v"(hdst), "v"(pk) : "memory");
      if (l == 0) {
        uint32_t* fdst = p.h0f + ((size_t)(d * 2 + par) << 15) + (size_t)pr * 512 + (pjg >> 1);
        const uint32_t hf =
            (uint32_t)__builtin_bit_cast(unsigned short, (_Float16)h0v) |
            ((uint32_t)__builtin_bit_cast(unsigned short, (_Float16)h1v) << 16);
        asm volatile("global_store_dword %0, %1, off sc0 sc1" ::"v"(fdst), "v"(hf) : "memory");
      } else {
        wred[pr * 16 + pj] = h0v * ww0;
        wred[pr * 16 + pj + 1] = h1v * ww1;
        __syncthreads();
        if (tid < 64) {
          float s = 0.f;
          #pragma unroll
          for (int q = 0; q < 16; ++q) s += wred[tid * 16 + q];
          p.wpart[((size_t)(d * 64 + j16) * S_LEN + td) * 64 + tid] = s;
        }
      }
    }

    // ---- flat 1-hop barrier: own flag store + parallel poll of all 128 ----
    __syncthreads();   // drains each wave's vmcnt -> h stores at coherence point
    if (tid == 0) {
      __hip_atomic_store(p.flags + (size_t)(d * 128 + idx) * 16, ph + 1,
                         __ATOMIC_RELAXED, __HIP_MEMORY_SCOPE_AGENT);
      asm volatile("s_waitcnt vmcnt(0)" ::: "memory");
    }
    if (tid < 128) {
      const int* fl = p.flags + (size_t)(d * 128 + tid) * 16;
      int f, it = 0;
      do {
        f = __hip_atomic_load(fl, __ATOMIC_RELAXED, __HIP_MEMORY_SCOPE_AGENT);
        if (f >= ph + 1) break;
        __builtin_amdgcn_s_sleep(1);
      } while (++it < (1 << 22));
    }
    __syncthreads();
  }
}

// w[b][t] = word_b + sum over (d,j16) of wpart
__global__ __launch_bounds__(64)
void reduce_w_kernel(const float* wpart, const float* wordb, float* w) {
  const int t = blockIdx.x, b = threadIdx.x;
  float s = wordb[0];
  #pragma unroll 8
  for (int q = 0; q < 128; ++q)
    s += wpart[((size_t)q * S_LEN + t) * 64 + b];
  w[b * S_LEN + t] = s;
}

__global__ __launch_bounds__(320)
void final_kernel(const float* w, const float* predW, const float* predb, float* out) {
  const int tid = threadIdx.x;
  if (tid >= B_SZ * NLBL) return;
  const int b = tid / NLBL, lab = tid % NLBL;
  float s = predb[lab];
  #pragma unroll 8
  for (int t = 0; t < S_LEN; ++t) s += w[b * S_LEN + t] * predW[t * NLBL + lab];
  out[tid] = s;
}

// ================= fallback path (proven round-2 kernels) =================
#define KC    128
#define NC    16
#define BKP   136
#define OFF_H0 0
#define OFF_H1 262144
#define OFF_C0 524288
#define OFF_C1 655360
#define OFF_W  786432
#define WS_TOTAL 794624

struct ParamsFB {
  const float* x;
  const float* W[2][3];
  const float* bias[2][3];
  const float* wordW;
  float* h0;
  float* h1;
  float* c0;
  float* c1;
  float* w;
};

__global__ __launch_bounds__(256)
void init_fb(float* ws, const float* hs, const float* cs, const float* wordb) {
  size_t i = (size_t)blockIdx.x * 256 + threadIdx.x;
  if (i < OFF_C0) {
    size_t be = i & (size_t)(B_SZ * E_SZ - 1);
    ws[i] = hs[be];
  } else if (i < OFF_W) {
    size_t be = (i - OFF_C0) & (size_t)(B_SZ * E_SZ - 1);
    ws[i] = cs[be];
  } else if (i < WS_TOTAL) {
    ws[i] = wordb[0];
  }
}

template<int LAYER>
__global__ __launch_bounds__(512)
void step_fb(ParamsFB p, int t) {
  __shared__ __align__(16) unsigned char lds_raw[53248];
  _Float16* BtBase = (_Float16*)lds_raw;
  float* pre = (float*)lds_raw;
  float* wcs = (float*)(lds_raw + 49152);

  const int tid = threadIdx.x;
  const int l = tid & 63;
  const int lr = l & 15;
  const int lg = l >> 4;
  const int wv = tid >> 6;
  const int kq = wv & 3;
  const int mg = wv >> 2;

  const int blk = blockIdx.x;
  const int jg = blk & 63;
  const int d = blk >> 6;
  const int j0 = jg * 16;
  const int td = d ? (S_LEN - 1 - t) : t;
  const int cur = t & 1, nxt = cur ^ 1;

  const float* hsrc = (LAYER == 0 ? p.h0 : p.h1) + (size_t)(d * 2 + cur) * (B_SZ * E_SZ);
  const float* isrc = (LAYER == 0) ? p.x : p.h0 + (size_t)(d * 2 + nxt) * (B_SZ * E_SZ);
  const float* Wg0 = p.W[d][0] + (size_t)LAYER * 2 * E_SZ * E_SZ;
  const float* Wg1 = p.W[d][1] + (size_t)LAYER * 2 * E_SZ * E_SZ;
  const float* Wg2 = p.W[d][2] + (size_t)LAYER * 2 * E_SZ * E_SZ;

  auto loadA = [&](int c, float4 dst[2][2]) {
    const int kk = c * KC + kq * 32 + lg * 8;
    #pragma unroll
    for (int mi = 0; mi < 2; ++mi) {
      const int row = (mg * 2 + mi) * 16 + lr;
      const float* ptr;
      if (kk < E_SZ) ptr = hsrc + (size_t)row * E_SZ + kk;
      else if (LAYER == 0) ptr = isrc + ((size_t)row * S_LEN + td) * E_SZ + (kk - E_SZ);
      else ptr = isrc + (size_t)row * E_SZ + (kk - E_SZ);
      dst[mi][0] = *(const float4*)ptr;
      dst[mi][1] = *(const float4*)(ptr + 4);
    }
  };
  auto loadB = [&](int c, float4 breg[3]) {
    #pragma unroll
    for (int it = 0; it < 3; ++it) {
      const int idx2 = tid + it * 512;
      const int row = idx2 >> 2;
      const int g = row >> 7;
      const int kk = row & 127;
      const int q = idx2 & 3;
      const float* W = (g == 0 ? Wg0 : (g == 1 ? Wg1 : Wg2));
      breg[it] = *(const float4*)(W + (size_t)(c * KC + kk) * E_SZ + j0 + q * 4);
    }
  };
  auto writeB = [&](const float4 breg[3], int buf) {
    _Float16* Bt = BtBase + buf * (48 * BKP);
    #pragma unroll
    for (int it = 0; it < 3; ++it) {
      const int idx2 = tid + it * 512;
      const int row = idx2 >> 2;
      const int g = row >> 7;
      const int kk = row & 127;
      const int q = idx2 & 3;
      #pragma unroll
      for (int jj = 0; jj < 4; ++jj)
        Bt[(g * 16 + q * 4 + jj) * BKP + kk] = (_Float16)breg[it][jj];
    }
  };

  float4 aCur[2][2], aNxt[2][2];
  float4 breg[3];
  loadB(0, breg);
  loadA(0, aCur);
  writeB(breg, 0);
  __syncthreads();

  const f32x4 zero = {0.f, 0.f, 0.f, 0.f};
  f32x4 acc[3][2];
  #pragma unroll
  for (int g = 0; g < 3; ++g) { acc[g][0] = zero; acc[g][1] = zero; }

  #pragma unroll
  for (int c = 0; c < NC; ++c) {
    half8 a1[2], a2[2];
    #pragma unroll
    for (int mi = 0; mi < 2; ++mi) {
      #pragma unroll
      for (int i = 0; i < 8; ++i) {
        const float v = (i < 4) ? aCur[mi][0][i] : aCur[mi][1][i - 4];
        const _Float16 h = (_Float16)v;
        a1[mi][i] = h;
        a2[mi][i] = (_Float16)(v - (float)h);
      }
    }
    if (c + 1 < NC) { loadB(c + 1, breg); loadA(c + 1, aNxt); }

    const _Float16* BtR = BtBase + (c & 1) * (48 * BKP) + kq * 32 + lg * 8;
    half8 bf[3];
    #pragma unroll
    for (int g = 0; g < 3; ++g)
      bf[g] = *(const half8*)(BtR + (g * 16 + lr) * BKP);

    #pragma unroll
    for (int g = 0; g < 3; ++g) {
      acc[g][0] = __builtin_amdgcn_mfma_f32_16x16x32_f16(a1[0], bf[g], acc[g][0], 0, 0, 0);
      acc[g][1] = __builtin_amdgcn_mfma_f32_16x16x32_f16(a1[1], bf[g], acc[g][1], 0, 0, 0);
    }
    #pragma unroll
    for (int g = 0; g < 3; ++g) {
      acc[g][0] = __builtin_amdgcn_mfma_f32_16x16x32_f16(a2[0], bf[g], acc[g][0], 0, 0, 0);
      acc[g][1] = __builtin_amdgcn_mfma_f32_16x16x32_f16(a2[1], bf[g], acc[g][1], 0, 0, 0);
    }

    if (c + 1 < NC) {
      writeB(breg, (c + 1) & 1);
      __syncthreads();
      #pragma unroll
      for (int mi = 0; mi < 2; ++mi) {
        aCur[mi][0] = aNxt[mi][0];
        aCur[mi][1] = aNxt[mi][1];
      }
    }
  }

  __syncthreads();
  #pragma unroll
  for (int g = 0; g < 3; ++g)
    #pragma unroll
    for (int mi = 0; mi < 2; ++mi)
      #pragma unroll
      for (int pp = 0; pp < 4; ++pp)
        pre[(((kq * 3 + g) * 64) + (mg * 2 + mi) * 16 + lg * 4 + pp) * 16 + lr] =
            acc[g][mi][pp];
  __syncthreads();

  float* cstf = (LAYER == 0 ? p.c0 : p.c1) + (size_t)d * (B_SZ * E_SZ);
  float* hdst = (LAYER == 0 ? p.h0 : p.h1) + (size_t)(d * 2 + nxt) * (B_SZ * E_SZ);

  #pragma unroll
  for (int rep = 0; rep < 2; ++rep) {
    const int e = tid + rep * 512;
    const int r = e >> 4;
    const int j = e & 15;
    const int jglob = j0 + j;
    float fp = p.bias[d][0][LAYER * E_SZ + jglob];
    float ip = p.bias[d][1][LAYER * E_SZ + jglob];
    float cp = p.bias[d][2][LAYER * E_SZ + jglob];
    #pragma unroll
    for (int k = 0; k < 4; ++k) {
      fp += pre[((k * 3 + 0) * 64 + r) * 16 + j];
      ip += pre[((k * 3 + 1) * 64 + r) * 16 + j];
      cp += pre[((k * 3 + 2) * 64 + r) * 16 + j];
    }
    const float fg = 1.f / (1.f + expf(-fp));
    const float ig = 1.f / (1.f + expf(-ip));
    const float gg = tanhf(cp);
    const float cold = cstf[(size_t)r * E_SZ + jglob];
    const float cnew = cold * fg + ig * gg;
    const float hnew = tanhf(cnew) * fg;
    cstf[(size_t)r * E_SZ + jglob] = cnew;
    hdst[(size_t)r * E_SZ + jglob] = hnew;
    if (LAYER == 1) wcs[r * 16 + j] = hnew * p.wordW[(size_t)d * E_SZ + jglob];
  }

  if (LAYER == 1) {
    __syncthreads();
    if (tid < 64) {
      float s = 0.f;
      #pragma unroll
      for (int q = 0; q < 16; ++q) s += wcs[tid * 16 + q];
      atomicAdd(&p.w[(size_t)tid * S_LEN + td], s);
    }
  }
}

// ================= launcher =================
extern "C" void kernel_launch(void* const* d_in, const int* in_sizes, int n_in,
                              void* d_out, int out_size, void* d_ws, size_t ws_size,
                              hipStream_t stream) {
  char* ws = (char*)d_ws;

  if (ws_size >= WS_NEED) {
    PP p;
    p.x = (const float*)d_in[0];
    p.W[0][0] = (const float*)d_in[5];  p.bias[0][0] = (const float*)d_in[6];
    p.W[0][1] = (const float*)d_in[7];  p.bias[0][1] = (const float*)d_in[8];
    p.W[0][2] = (const float*)d_in[9];  p.bias[0][2] = (const float*)d_in[10];
    p.W[1][0] = (const float*)d_in[11]; p.bias[1][0] = (const float*)d_in[12];
    p.W[1][1] = (const float*)d_in[13]; p.bias[1][1] = (const float*)d_in[14];
    p.W[1][2] = (const float*)d_in[15]; p.bias[1][2] = (const float*)d_in[16];
    p.wordW = (const float*)d_in[17];
    p.cs0   = (const float*)d_in[1];
    p.wrec  = (_Float16*)(ws + WOFF_WREC);
    p.winp  = (_Float16*)(ws + WOFF_WINP);
    p.x16   = (_Float16*)(ws + WOFF_X16);
    p.h0    = (uint32_t*)(ws + WOFF_H0);
    p.h1    = (uint32_t*)(ws + WOFF_H1);
    p.h0f   = (uint32_t*)(ws + WOFF_H0F);
    p.w     = (float*)(ws + WOFF_W);
    p.wpart = (float*)(ws + WOFF_WPART);
    p.flags = (int*)(ws + WOFF_FLAGS);

    hipFuncSetAttribute((const void*)lstm_persist,
                        hipFuncAttributeMaxDynamicSharedMemorySize, 151552);

    conv_w_kernel<<<1536, 256, 0, stream>>>(p);
    conv_x_kernel<<<4096, 256, 0, stream>>>(p.x, p.x16);
    init2_kernel<<<(INIT_TOTAL + 255) / 256, 256, 0, stream>>>(p, (const float*)d_in[2]);
    lstm_persist<<<256, 512, 151552, stream>>>(p);
    reduce_w_kernel<<<128, 64, 0, stream>>>(p.wpart, (const float*)d_in[18], p.w);
    final_kernel<<<1, 320, 0, stream>>>(p.w, (const float*)d_in[19],
                                        (const float*)d_in[20], (float*)d_out);
  } else {
    float* wsf = (float*)d_ws;
    ParamsFB p;
    p.x = (const float*)d_in[0];
    p.W[0][0] = (const float*)d_in[5];  p.bias[0][0] = (const float*)d_in[6];
    p.W[0][1] = (const float*)d_in[7];  p.bias[0][1] = (const float*)d_in[8];
    p.W[0][2] = (const float*)d_in[9];  p.bias[0][2] = (const float*)d_in[10];
    p.W[1][0] = (const float*)d_in[11]; p.bias[1][0] = (const float*)d_in[12];
    p.W[1][1] = (const float*)d_in[13]; p.bias[1][1] = (const float*)d_in[14];
    p.W[1][2] = (const float*)d_in[15]; p.bias[1][2] = (const float*)d_in[16];
    p.wordW = (const float*)d_in[17];
    p.h0 = wsf + OFF_H0;
    p.h1 = wsf + OFF_H1;
    p.c0 = wsf + OFF_C0;
    p.c1 = wsf + OFF_C1;
    p.w  = wsf + OFF_W;

    init_fb<<<WS_TOTAL / 256, 256, 0, stream>>>(
        wsf, (const float*)d_in[2], (const float*)d_in[1], (const float*)d_in[18]);
    for (int t = 0; t < S_LEN; ++t) {
      step_fb<0><<<128, 512, 0, stream>>>(p, t);
      step_fb<1><<<128, 512, 0, stream>>>(p, t);
    }
    final_kernel<<<1, 320, 0, stream>>>(p.w, (const float*)d_in[19],
                                        (const float*)d_in[20], (float*)d_out);
  }
}

// Round 9
// 1530.186 us; speedup vs baseline: 14.8200x; 1.3022x over previous
//
#include <hip/hip_runtime.h>
#include <cstddef>
#include <cstdint>

typedef _Float16 half8 __attribute__((ext_vector_type(8)));
typedef float f32x4 __attribute__((ext_vector_type(4)));

#define S_LEN 128
#define B_SZ  64
#define E_SZ  1024
#define NLBL  5
#define NPHASE 129

// ---------------- ws layouts (bytes) ----------------
// common: wrec 0..25165824, winp ..50331648, x16 ..67108864
#define WOFF_WREC  0ull
#define WOFF_WINP  25165824ull
#define WOFF_X16   50331648ull
// MODE0 (history): h0 [2][129][64][1024] f16, h1 same
#define M0_H0    67108864ull
#define M0_H1    100925440ull
#define M0_WPART 134742016ull
#define M0_W     138936320ull
#define M0_FLAGS 138969088ull
#define NEED0    139001856ull
// MODE1 (2-buffer): h0 [2][2][64][1024] f16, h1 same
#define M1_H0    67108864ull
#define M1_H1    67633152ull
#define M1_WPART 68157440ull
#define M1_W     72351744ull
#define M1_FLAGS 72384512ull
#define NEED1    72417280ull

struct PP {
  const float* x;
  const float* W[2][3];
  const float* bias[2][3];
  const float* wordW;
  const float* cs0;
  _Float16* wrec;   // [(d*2+l)*64+j16][g*16384 + kc*512 + lane*8 + e] f16
  _Float16* winp;
  _Float16* x16;    // [B][S][E] f16
  _Float16* h0;     // MODE0: [2][129][64][1024]; MODE1: [2][2][64][1024]
  _Float16* h1;
  float* w;         // [64][128]
  float* wpart;     // [2d][64 j16][128 t][64 b]
  int* flags;       // [2d][128] stride-32 ints (128B)
};

__device__ __forceinline__ uint32_t pack2f16(float a, float b) {
  return (uint32_t)__builtin_bit_cast(unsigned short, (_Float16)a) |
         ((uint32_t)__builtin_bit_cast(unsigned short, (_Float16)b) << 16);
}

#define MFMA16(A, B, C) __builtin_amdgcn_mfma_f32_16x16x32_f16(A, B, C, 0, 0, 0)

// ---- issue asm primitives (outputs only -> no tied operands) ----
#define S_ISSUE_A4C(Q, P0, P1, P2, P3)                                     \
  asm volatile("global_load_dwordx4 %0, %4, off sc0 sc1\n\t"               \
               "global_load_dwordx4 %1, %5, off sc0 sc1\n\t"               \
               "global_load_dwordx4 %2, %6, off sc0 sc1\n\t"               \
               "global_load_dwordx4 %3, %7, off sc0 sc1"                   \
               : "=&v"((Q)[0]), "=&v"((Q)[1]), "=&v"((Q)[2]), "=&v"((Q)[3]) \
               : "v"(P0), "v"(P1), "v"(P2), "v"(P3))

#define S_ISSUE_A4P(Q, P0, P1, P2, P3)                                     \
  asm volatile("global_load_dwordx4 %0, %4, off\n\t"                       \
               "global_load_dwordx4 %1, %5, off\n\t"                       \
               "global_load_dwordx4 %2, %6, off\n\t"                       \
               "global_load_dwordx4 %3, %7, off"                           \
               : "=&v"((Q)[0]), "=&v"((Q)[1]), "=&v"((Q)[2]), "=&v"((Q)[3]) \
               : "v"(P0), "v"(P1), "v"(P2), "v"(P3))

#define S_ISSUE_W6(Q, P0, P1, P2, P3, P4, P5)                              \
  asm volatile("global_load_dwordx4 %0, %6, off\n\t"                       \
               "global_load_dwordx4 %1, %7, off\n\t"                       \
               "global_load_dwordx4 %2, %8, off\n\t"                       \
               "global_load_dwordx4 %3, %9, off\n\t"                       \
               "global_load_dwordx4 %4, %10, off\n\t"                      \
               "global_load_dwordx4 %5, %11, off"                          \
               : "=&v"((Q)[0]), "=&v"((Q)[1]), "=&v"((Q)[2]), "=&v"((Q)[3]), \
                 "=&v"((Q)[4]), "=&v"((Q)[5])                              \
               : "v"(P0), "v"(P1), "v"(P2), "v"(P3), "v"(P4), "v"(P5))

// counted wait: bare asm + sched_barrier fence (rule-18 pattern)
#define S_WAITV(N)                                                         \
  asm volatile("s_waitcnt vmcnt(" #N ")" ::: "memory");                    \
  __builtin_amdgcn_sched_barrier(0)

// q[0],q[1] = m-tiles @ kcA; q[2],q[3] = m-tiles @ kcA+1; B from LDS
__device__ __forceinline__ void comp_rec2s(const uint4* q, int kcA,
                                           const _Float16* wlds, int l64,
                                           f32x4 acc[3][2]) {
  #pragma unroll
  for (int s = 0; s < 2; ++s) {
    const int kc = kcA + s;
    const half8 a0 = __builtin_bit_cast(half8, q[s * 2 + 0]);
    const half8 a1 = __builtin_bit_cast(half8, q[s * 2 + 1]);
    #pragma unroll
    for (int g = 0; g < 3; ++g) {
      const half8 bf = *(const half8*)(wlds + ((size_t)(g * 32 + kc) * 64 + l64) * 8);
      acc[g][0] = MFMA16(a0, bf, acc[g][0]);
      acc[g][1] = MFMA16(a1, bf, acc[g][1]);
    }
  }
}

__device__ __forceinline__ void comp_inp2(const uint4* aq, const uint4* wq,
                                          f32x4 acc[3][2]) {
  #pragma unroll
  for (int s = 0; s < 2; ++s) {
    const half8 a0 = __builtin_bit_cast(half8, aq[s * 2 + 0]);
    const half8 a1 = __builtin_bit_cast(half8, aq[s * 2 + 1]);
    #pragma unroll
    for (int g = 0; g < 3; ++g) {
      const half8 bf = __builtin_bit_cast(half8, wq[s * 3 + g]);
      acc[g][0] = MFMA16(a0, bf, acc[g][0]);
      acc[g][1] = MFMA16(a1, bf, acc[g][1]);
    }
  }
}

// -------- conversion kernels (run every launch; deterministic) --------
__global__ __launch_bounds__(256)
void conv_w_kernel(PP p) {
  const int blk = blockIdx.x;           // (((d*2+l)*3+g)*64 + j16)*2 + part
  const int part = blk & 1;
  const int j16 = (blk >> 1) & 63;
  const int rest = blk >> 7;
  const int g = rest % 3;
  const int dl = rest / 3;
  const int l = dl & 1, d = dl >> 1;
  const int tid = threadIdx.x;
  const int l2 = tid & 63, kc0 = tid >> 6;
  const float* W = p.W[d][g] + (size_t)l * 2048 * 1024 + (size_t)(part ? 1024 : 0) * 1024;
  _Float16* out = (part ? p.winp : p.wrec) + (size_t)(dl * 64 + j16) * 49152 + (size_t)g * 16384;
  const int j = j16 * 16 + (l2 & 15);
  const int kbase = (l2 >> 4) * 8;
  #pragma unroll
  for (int ki = 0; ki < 8; ++ki) {
    const int kc = kc0 * 8 + ki;
    const int k0 = kc * 32 + kbase;
    half8 h;
    #pragma unroll
    for (int e2 = 0; e2 < 8; ++e2) h[e2] = (_Float16)W[(size_t)(k0 + e2) * 1024 + j];
    *(half8*)(out + ((size_t)kc * 64 + l2) * 8) = h;
  }
}

__global__ __launch_bounds__(256)
void conv_x_kernel(const float* x, _Float16* x16) {
  const size_t i8 = ((size_t)blockIdx.x * 256 + threadIdx.x) * 8;
  float4 a = *(const float4*)(x + i8);
  float4 b = *(const float4*)(x + i8 + 4);
  half8 h;
  h[0] = (_Float16)a.x; h[1] = (_Float16)a.y; h[2] = (_Float16)a.z; h[3] = (_Float16)a.w;
  h[4] = (_Float16)b.x; h[5] = (_Float16)b.y; h[6] = (_Float16)b.z; h[7] = (_Float16)b.w;
  *(half8*)(x16 + i8) = h;
}

// MODE0: fill slot 0 of h0/h1 hist; MODE1: fill both par buffers. Then flags.
template<int MODE>
__global__ __launch_bounds__(256)
void init2_kernel(PP p, const float* hs) {
  const size_t HU = (MODE == 0) ? 65536 : 131072;  // u32 words per h array
  const size_t i = (size_t)blockIdx.x * 256 + threadIdx.x;
  if (i < 2 * HU) {
    const size_t ai = (i < HU) ? i : i - HU;
    _Float16* dst = (i < HU) ? p.h0 : p.h1;
    const size_t grp = ai >> 15;            // MODE0: d (0..1); MODE1: d*2+par (0..3)
    const size_t be = ai & 32767;           // [64][512] u32
    const size_t b = be >> 9, ec = be & 511;
    const uint32_t v = pack2f16(hs[b * 1024 + ec * 2], hs[b * 1024 + ec * 2 + 1]);
    const size_t u32off = (MODE == 0) ? (grp * 129 * 32768 + be) : (grp * 32768 + be);
    ((uint32_t*)dst)[u32off] = v;
  } else if (i < 2 * HU + 8192) {
    p.flags[i - 2 * HU] = 0;
  }
}

// ---------------- persistent bidirectional LSTM ----------------
// MODE0: time-indexed h history, plain cached h loads (L2 multicast).
// MODE1: 2-buffer h, coherence-point (sc0 sc1) loads.
template<int MODE>
__global__ __launch_bounds__(512, 2)
void lstm_persist(PP p) {
  extern __shared__ char smem[];
  _Float16* wlds = (_Float16*)smem;            // 98304 B: rec weights
  float* pre  = (float*)(smem + 98304);        // 768 rows x stride 18 f32 = 55296 B
  float* wred = (float*)(smem + 153600);       // 4096 B

  const int tid = threadIdx.x;
  const int l64 = tid & 63, lr = l64 & 15, lg = l64 >> 4;
  const int wv = tid >> 6, kq = wv & 3, mg = wv >> 2;
  const int blk = blockIdx.x;
  const int j16 = blk & 63, l = (blk >> 6) & 1, d = blk >> 7;
  const int idx = blk & 127;
  const int j0 = j16 * 16;

  // kill stale L1/L2 lines from previous graph replays (one buffer_inv/block)
  if (tid == 0)
    (void)__hip_atomic_load(p.flags, __ATOMIC_ACQUIRE, __HIP_MEMORY_SCOPE_AGENT);
  __syncthreads();

  const size_t tileoff = (size_t)((d * 2 + l) * 64 + j16) * 49152;
  {
    const float4* src = (const float4*)(p.wrec + tileoff);
    float4* dst = (float4*)wlds;
    #pragma unroll
    for (int i = 0; i < 12; ++i) dst[tid + i * 512] = src[tid + i * 512];
  }
  const _Float16* wtile = p.winp + tileoff;
  _Float16* hrec_arr = l ? p.h1 : p.h0;

  // ---- prologue hoists: bias / wordW / c-state live in registers ----
  const int pr = tid >> 3;          // pointwise row 0..63
  const int pj = (tid & 7) * 2;     // pointwise col pair
  const int pjg = j0 + pj;
  const float bsf0 = p.bias[d][0][l * E_SZ + pjg], bsf1 = p.bias[d][0][l * E_SZ + pjg + 1];
  const float bsi0 = p.bias[d][1][l * E_SZ + pjg], bsi1 = p.bias[d][1][l * E_SZ + pjg + 1];
  const float bsc0 = p.bias[d][2][l * E_SZ + pjg], bsc1 = p.bias[d][2][l * E_SZ + pjg + 1];
  const float ww0 = p.wordW[d * E_SZ + pjg], ww1 = p.wordW[d * E_SZ + pjg + 1];
  float creg0 = p.cs0[(size_t)pr * E_SZ + pjg];
  float creg1 = p.cs0[(size_t)pr * E_SZ + pjg + 1];
  __syncthreads();

  auto hoff = [&](int dd, int s) -> size_t {
    return (MODE == 0) ? ((size_t)dd * 129 + s) * 65536 : ((size_t)(dd * 2 + s)) * 65536;
  };

  for (int ph = 0; ph < NPHASE; ++ph) {
    const int t = l ? (ph - 1) : ph;
    if ((unsigned)t < (unsigned)S_LEN) {
      const int par = t & 1, prev = par ^ 1;
      const int td = d ? (S_LEN - 1 - t) : t;
      const int rs    = (MODE == 0) ? t : prev;       // recurrent read slot
      const int wslot = (MODE == 0) ? (t + 1) : par;  // write slot
      const int islot = (MODE == 0) ? (t + 1) : par;  // l1 input slot (h0)

      const _Float16* hAf = hrec_arr + hoff(d, rs);
      const _Float16* r0 = hAf + (size_t)(mg * 32 + lr) * 1024;
      const _Float16* r1 = hAf + (size_t)(mg * 32 + 16 + lr) * 1024;
      const _Float16* a0base;
      const _Float16* a1base;
      if (l == 0) {
        a0base = p.x16 + ((size_t)(mg * 32 + lr) * S_LEN + td) * 1024;
        a1base = p.x16 + ((size_t)(mg * 32 + 16 + lr) * S_LEN + td) * 1024;
      } else {
        const _Float16* hf = p.h0 + hoff(d, islot);
        a0base = hf + (size_t)(mg * 32 + lr) * 1024;
        a1base = hf + (size_t)(mg * 32 + 16 + lr) * 1024;
      }

      const f32x4 zero = {0.f, 0.f, 0.f, 0.f};
      f32x4 acc[3][2];
      #pragma unroll
      for (int g = 0; g < 3; ++g) { acc[g][0] = zero; acc[g][1] = zero; }

      auto issue_rec = [&](int c, uint4* Q) {
        const int kk = (kq * 8 + c * 2) * 32 + lg * 8;
        if (MODE == 0) {
          S_ISSUE_A4P(Q, r0 + kk, r1 + kk, r0 + kk + 32, r1 + kk + 32);
        } else {
          S_ISSUE_A4C(Q, r0 + kk, r1 + kk, r0 + kk + 32, r1 + kk + 32);
        }
      };
      auto issue_a = [&](int c, uint4* Q) {
        const int kk = (kq * 8 + c * 2) * 32 + lg * 8;
        if (MODE == 0 || l == 0) {
          S_ISSUE_A4P(Q, a0base + kk, a1base + kk, a0base + kk + 32, a1base + kk + 32);
        } else {
          S_ISSUE_A4C(Q, a0base + kk, a1base + kk, a0base + kk + 32, a1base + kk + 32);
        }
      };
      auto issue_w = [&](int c, uint4* Q) {
        const int kc0 = kq * 8 + c * 2;
        S_ISSUE_W6(Q,
                   wtile + ((size_t)(0 * 32 + kc0) * 64 + l64) * 8,
                   wtile + ((size_t)(1 * 32 + kc0) * 64 + l64) * 8,
                   wtile + ((size_t)(2 * 32 + kc0) * 64 + l64) * 8,
                   wtile + ((size_t)(0 * 32 + kc0 + 1) * 64 + l64) * 8,
                   wtile + ((size_t)(1 * 32 + kc0 + 1) * 64 + l64) * 8,
                   wtile + ((size_t)(2 * 32 + kc0 + 1) * 64 + l64) * 8);
      };

      uint4 rq[2][4], aq[2][4], wq[2][6];
      // ---- depth-1 pipelined schedule, counted vmcnt ----
      issue_rec(0, rq[0]);
      issue_rec(1, rq[1]); S_WAITV(4);  comp_rec2s(rq[0], kq * 8 + 0, wlds, l64, acc);
      issue_rec(2, rq[0]); S_WAITV(4);  comp_rec2s(rq[1], kq * 8 + 2, wlds, l64, acc);
      issue_rec(3, rq[1]); S_WAITV(4);  comp_rec2s(rq[0], kq * 8 + 4, wlds, l64, acc);
      issue_a(0, aq[0]); issue_w(0, wq[0]);
      S_WAITV(10);                      comp_rec2s(rq[1], kq * 8 + 6, wlds, l64, acc);
      issue_a(1, aq[1]); issue_w(1, wq[1]);
      S_WAITV(10);                      comp_inp2(aq[0], wq[0], acc);
      issue_a(2, aq[0]); issue_w(2, wq[0]);
      S_WAITV(10);                      comp_inp2(aq[1], wq[1], acc);
      issue_a(3, aq[1]); issue_w(3, wq[1]);
      S_WAITV(10);                      comp_inp2(aq[0], wq[0], acc);
      S_WAITV(0);                       comp_inp2(aq[1], wq[1], acc);

      // ---- reduce kq partials (stride-18 pad: 4*18 = 8 mod 32 -> 2-way max) ----
      #pragma unroll
      for (int g = 0; g < 3; ++g)
        #pragma unroll
        for (int mt = 0; mt < 2; ++mt)
          #pragma unroll
          for (int pp = 0; pp < 4; ++pp)
            pre[(((kq * 3 + g) * 64) + (mg * 2 + mt) * 16 + lg * 4 + pp) * 18 + lr] =
                acc[g][mt][pp];
      __syncthreads();

      // ---- pointwise LSTM update (1 row x 2 cols per thread) ----
      float fp0 = bsf0, fp1 = bsf1, ip0 = bsi0, ip1 = bsi1, cp0 = bsc0, cp1 = bsc1;
      #pragma unroll
      for (int k = 0; k < 4; ++k) {
        fp0 += pre[((k * 3 + 0) * 64 + pr) * 18 + pj];
        fp1 += pre[((k * 3 + 0) * 64 + pr) * 18 + pj + 1];
        ip0 += pre[((k * 3 + 1) * 64 + pr) * 18 + pj];
        ip1 += pre[((k * 3 + 1) * 64 + pr) * 18 + pj + 1];
        cp0 += pre[((k * 3 + 2) * 64 + pr) * 18 + pj];
        cp1 += pre[((k * 3 + 2) * 64 + pr) * 18 + pj + 1];
      }
      const float fg0 = 1.f / (1.f + expf(-fp0)), fg1 = 1.f / (1.f + expf(-fp1));
      const float ig0 = 1.f / (1.f + expf(-ip0)), ig1 = 1.f / (1.f + expf(-ip1));
      const float gg0 = tanhf(cp0), gg1 = tanhf(cp1);
      creg0 = creg0 * fg0 + ig0 * gg0;
      creg1 = creg1 * fg1 + ig1 * gg1;
      const float h0v = tanhf(creg0) * fg0;    // forget gate reused as output gate
      const float h1v = tanhf(creg1) * fg1;

      uint32_t* hdst = (uint32_t*)(hrec_arr + hoff(d, wslot) + (size_t)pr * 1024 + pjg);
      const uint32_t pk = pack2f16(h0v, h1v);
      asm volatile("global_store_dword %0, %1, off sc0 sc1" ::"v"(hdst), "v"(pk) : "memory");
      if (l) {
        wred[pr * 16 + pj] = h0v * ww0;
        wred[pr * 16 + pj + 1] = h1v * ww1;
        __syncthreads();
        if (tid < 64) {
          float s = 0.f;
          #pragma unroll
          for (int q = 0; q < 16; ++q) s += wred[tid * 16 + q];
          p.wpart[((size_t)(d * 64 + j16) * S_LEN + td) * 64 + tid] = s;
        }
      }
    }

    // ---- flat 1-hop barrier: own flag store + parallel poll of all 128 ----
    __syncthreads();   // drains each wave's vmcnt -> h stores at coherence point
    if (tid == 0) {
      __hip_atomic_store(p.flags + (size_t)(d * 128 + idx) * 32, ph + 1,
                         __ATOMIC_RELAXED, __HIP_MEMORY_SCOPE_AGENT);
      asm volatile("s_waitcnt vmcnt(0)" ::: "memory");
    }
    if (tid < 128) {
      const int* fl = p.flags + (size_t)(d * 128 + tid) * 32;
      int f, it = 0;
      do {
        f = __hip_atomic_load(fl, __ATOMIC_RELAXED, __HIP_MEMORY_SCOPE_AGENT);
        if (f >= ph + 1) break;
        __builtin_amdgcn_s_sleep(1);
      } while (++it < (1 << 22));
    }
    __syncthreads();
  }
}

// w[b][t] = word_b + sum over (d,j16) of wpart
__global__ __launch_bounds__(64)
void reduce_w_kernel(const float* wpart, const float* wordb, float* w) {
  const int t = blockIdx.x, b = threadIdx.x;
  float s = wordb[0];
  #pragma unroll 8
  for (int q = 0; q < 128; ++q)
    s += wpart[((size_t)q * S_LEN + t) * 64 + b];
  w[b * S_LEN + t] = s;
}

__global__ __launch_bounds__(320)
void final_kernel(const float* w, const float* predW, const float* predb, float* out) {
  const int tid = threadIdx.x;
  if (tid >= B_SZ * NLBL) return;
  const int b = tid / NLBL, lab = tid % NLBL;
  float s = predb[lab];
  #pragma unroll 8
  for (int t = 0; t < S_LEN; ++t) s += w[b * S_LEN + t] * predW[t * NLBL + lab];
  out[tid] = s;
}

// ================= launcher =================
extern "C" void kernel_launch(void* const* d_in, const int* in_sizes, int n_in,
                              void* d_out, int out_size, void* d_ws, size_t ws_size,
                              hipStream_t stream) {
  char* ws = (char*)d_ws;
  const bool hist = (ws_size >= NEED0);

  PP p;
  p.x = (const float*)d_in[0];
  p.W[0][0] = (const float*)d_in[5];  p.bias[0][0] = (const float*)d_in[6];
  p.W[0][1] = (const float*)d_in[7];  p.bias[0][1] = (const float*)d_in[8];
  p.W[0][2] = (const float*)d_in[9];  p.bias[0][2] = (const float*)d_in[10];
  p.W[1][0] = (const float*)d_in[11]; p.bias[1][0] = (const float*)d_in[12];
  p.W[1][1] = (const float*)d_in[13]; p.bias[1][1] = (const float*)d_in[14];
  p.W[1][2] = (const float*)d_in[15]; p.bias[1][2] = (const float*)d_in[16];
  p.wordW = (const float*)d_in[17];
  p.cs0   = (const float*)d_in[1];
  p.wrec  = (_Float16*)(ws + WOFF_WREC);
  p.winp  = (_Float16*)(ws + WOFF_WINP);
  p.x16   = (_Float16*)(ws + WOFF_X16);
  if (hist) {
    p.h0    = (_Float16*)(ws + M0_H0);
    p.h1    = (_Float16*)(ws + M0_H1);
    p.wpart = (float*)(ws + M0_WPART);
    p.w     = (float*)(ws + M0_W);
    p.flags = (int*)(ws + M0_FLAGS);
  } else {
    p.h0    = (_Float16*)(ws + M1_H0);
    p.h1    = (_Float16*)(ws + M1_H1);
    p.wpart = (float*)(ws + M1_WPART);
    p.w     = (float*)(ws + M1_W);
    p.flags = (int*)(ws + M1_FLAGS);
  }

  hipFuncSetAttribute(reinterpret_cast<const void*>(&lstm_persist<0>),
                      hipFuncAttributeMaxDynamicSharedMemorySize, 157696);
  hipFuncSetAttribute(reinterpret_cast<const void*>(&lstm_persist<1>),
                      hipFuncAttributeMaxDynamicSharedMemorySize, 157696);

  conv_w_kernel<<<1536, 256, 0, stream>>>(p);
  conv_x_kernel<<<4096, 256, 0, stream>>>(p.x, p.x16);
  if (hist) {
    init2_kernel<0><<<544, 256, 0, stream>>>(p, (const float*)d_in[2]);
    lstm_persist<0><<<256, 512, 157696, stream>>>(p);
  } else {
    init2_kernel<1><<<1056, 256, 0, stream>>>(p, (const float*)d_in[2]);
    lstm_persist<1><<<256, 512, 157696, stream>>>(p);
  }
  reduce_w_kernel<<<128, 64, 0, stream>>>(p.wpart, (const float*)d_in[18], p.w);
  final_kernel<<<1, 320, 0, stream>>>(p.w, (const float*)d_in[19],
                                      (const float*)d_in[20], (float*)d_out);
}

// Round 10
// 1360.087 us; speedup vs baseline: 16.6734x; 1.1251x over previous
//
#include <hip/hip_runtime.h>
#include <cstddef>
#include <cstdint>

typedef _Float16 half8 __attribute__((ext_vector_type(8)));
typedef float f32x4 __attribute__((ext_vector_type(4)));

#define S_LEN 128
#define B_SZ  64
#define E_SZ  1024
#define NLBL  5
#define NPHASE 129

// ---------------- ws layouts (bytes) ----------------
#define WOFF_WREC  0ull
#define WOFF_WINP  25165824ull
#define WOFF_X16   50331648ull
// MODE0 (history): h0 [2][129][64][1024] f16, h1 same
#define M0_H0    67108864ull
#define M0_H1    100925440ull
#define M0_WPART 134742016ull
#define M0_W     138936320ull
#define M0_FLAGS 138969088ull
#define NEED0    139001856ull
// MODE1 (2-buffer): h0 [2][2][64][1024] f16, h1 same
#define M1_H0    67108864ull
#define M1_H1    67633152ull
#define M1_WPART 68157440ull
#define M1_W     72351744ull
#define M1_FLAGS 72384512ull
#define NEED1    72417280ull

struct PP {
  const float* x;
  const float* W[2][3];
  const float* bias[2][3];
  const float* wordW;
  const float* cs0;
  _Float16* wrec;   // [(d*2+l)*64+j16][g*16384 + kc*512 + lane*8 + e] f16
  _Float16* winp;
  _Float16* x16;    // [B][S][E] f16
  _Float16* h0;     // MODE0: [2][129][64][1024]; MODE1: [2][2][64][1024]
  _Float16* h1;
  float* w;         // [64][128]
  float* wpart;     // [2d][64 j16][128 t][64 b]
  int* flags;       // [2d][128] stride-32 ints (128B)
};

__device__ __forceinline__ uint32_t pack2f16(float a, float b) {
  return (uint32_t)__builtin_bit_cast(unsigned short, (_Float16)a) |
         ((uint32_t)__builtin_bit_cast(unsigned short, (_Float16)b) << 16);
}

#define MFMA16(A, B, C) __builtin_amdgcn_mfma_f32_16x16x32_f16(A, B, C, 0, 0, 0)

// ---- issue asm primitives (outputs only -> no tied operands) ----
#define S_ISSUE_A4C(Q, P0, P1, P2, P3)                                     \
  asm volatile("global_load_dwordx4 %0, %4, off sc0 sc1\n\t"               \
               "global_load_dwordx4 %1, %5, off sc0 sc1\n\t"               \
               "global_load_dwordx4 %2, %6, off sc0 sc1\n\t"               \
               "global_load_dwordx4 %3, %7, off sc0 sc1"                   \
               : "=&v"((Q)[0]), "=&v"((Q)[1]), "=&v"((Q)[2]), "=&v"((Q)[3]) \
               : "v"(P0), "v"(P1), "v"(P2), "v"(P3))

#define S_ISSUE_A4P(Q, P0, P1, P2, P3)                                     \
  asm volatile("global_load_dwordx4 %0, %4, off\n\t"                       \
               "global_load_dwordx4 %1, %5, off\n\t"                       \
               "global_load_dwordx4 %2, %6, off\n\t"                       \
               "global_load_dwordx4 %3, %7, off"                           \
               : "=&v"((Q)[0]), "=&v"((Q)[1]), "=&v"((Q)[2]), "=&v"((Q)[3]) \
               : "v"(P0), "v"(P1), "v"(P2), "v"(P3))

// counted wait: bare asm + sched_barrier fence (rule-18 pattern)
#define S_WAITV(N)                                                         \
  asm volatile("s_waitcnt vmcnt(" #N ")" ::: "memory");                    \
  __builtin_amdgcn_sched_barrier(0)

// q[0],q[1] = m-tiles @ kcA; q[2],q[3] = m-tiles @ kcA+1; B from LDS
__device__ __forceinline__ void comp_rec2s(const uint4* q, int kcA,
                                           const _Float16* wlds, int l64,
                                           f32x4 acc[3][2]) {
  #pragma unroll
  for (int s = 0; s < 2; ++s) {
    const int kc = kcA + s;
    const half8 a0 = __builtin_bit_cast(half8, q[s * 2 + 0]);
    const half8 a1 = __builtin_bit_cast(half8, q[s * 2 + 1]);
    #pragma unroll
    for (int g = 0; g < 3; ++g) {
      const half8 bf = *(const half8*)(wlds + ((size_t)(g * 32 + kc) * 64 + l64) * 8);
      acc[g][0] = MFMA16(a0, bf, acc[g][0]);
      acc[g][1] = MFMA16(a1, bf, acc[g][1]);
    }
  }
}

// B from registers (winp slice)
__device__ __forceinline__ void comp_inp2(const uint4* aq, const uint4* wq,
                                          f32x4 acc[3][2]) {
  #pragma unroll
  for (int s = 0; s < 2; ++s) {
    const half8 a0 = __builtin_bit_cast(half8, aq[s * 2 + 0]);
    const half8 a1 = __builtin_bit_cast(half8, aq[s * 2 + 1]);
    #pragma unroll
    for (int g = 0; g < 3; ++g) {
      const half8 bf = __builtin_bit_cast(half8, wq[s * 3 + g]);
      acc[g][0] = MFMA16(a0, bf, acc[g][0]);
      acc[g][1] = MFMA16(a1, bf, acc[g][1]);
    }
  }
}

// -------- conversion kernels (run every launch; deterministic) --------
__global__ __launch_bounds__(256)
void conv_w_kernel(PP p) {
  const int blk = blockIdx.x;           // (((d*2+l)*3+g)*64 + j16)*2 + part
  const int part = blk & 1;
  const int j16 = (blk >> 1) & 63;
  const int rest = blk >> 7;
  const int g = rest % 3;
  const int dl = rest / 3;
  const int l = dl & 1, d = dl >> 1;
  const int tid = threadIdx.x;
  const int l2 = tid & 63, kc0 = tid >> 6;
  const float* W = p.W[d][g] + (size_t)l * 2048 * 1024 + (size_t)(part ? 1024 : 0) * 1024;
  _Float16* out = (part ? p.winp : p.wrec) + (size_t)(dl * 64 + j16) * 49152 + (size_t)g * 16384;
  const int j = j16 * 16 + (l2 & 15);
  const int kbase = (l2 >> 4) * 8;
  #pragma unroll
  for (int ki = 0; ki < 8; ++ki) {
    const int kc = kc0 * 8 + ki;
    const int k0 = kc * 32 + kbase;
    half8 h;
    #pragma unroll
    for (int e2 = 0; e2 < 8; ++e2) h[e2] = (_Float16)W[(size_t)(k0 + e2) * 1024 + j];
    *(half8*)(out + ((size_t)kc * 64 + l2) * 8) = h;
  }
}

__global__ __launch_bounds__(256)
void conv_x_kernel(const float* x, _Float16* x16) {
  const size_t i8 = ((size_t)blockIdx.x * 256 + threadIdx.x) * 8;
  float4 a = *(const float4*)(x + i8);
  float4 b = *(const float4*)(x + i8 + 4);
  half8 h;
  h[0] = (_Float16)a.x; h[1] = (_Float16)a.y; h[2] = (_Float16)a.z; h[3] = (_Float16)a.w;
  h[4] = (_Float16)b.x; h[5] = (_Float16)b.y; h[6] = (_Float16)b.z; h[7] = (_Float16)b.w;
  *(half8*)(x16 + i8) = h;
}

// MODE0: fill slot 0 of h0/h1 hist; MODE1: fill both par buffers. Then flags.
template<int MODE>
__global__ __launch_bounds__(256)
void init2_kernel(PP p, const float* hs) {
  const size_t HU = (MODE == 0) ? 65536 : 131072;  // u32 words per h array
  const size_t i = (size_t)blockIdx.x * 256 + threadIdx.x;
  if (i < 2 * HU) {
    const size_t ai = (i < HU) ? i : i - HU;
    _Float16* dst = (i < HU) ? p.h0 : p.h1;
    const size_t grp = ai >> 15;            // MODE0: d (0..1); MODE1: d*2+par (0..3)
    const size_t be = ai & 32767;           // [64][512] u32
    const size_t b = be >> 9, ec = be & 511;
    const uint32_t v = pack2f16(hs[b * 1024 + ec * 2], hs[b * 1024 + ec * 2 + 1]);
    const size_t u32off = (MODE == 0) ? (grp * 129 * 32768 + be) : (grp * 32768 + be);
    ((uint32_t*)dst)[u32off] = v;
  } else if (i < 2 * HU + 8192) {
    p.flags[i - 2 * HU] = 0;
  }
}

// ---------------- persistent bidirectional LSTM ----------------
template<int MODE>
__global__ __launch_bounds__(512, 2)
void lstm_persist(PP p) {
  extern __shared__ char smem[];
  _Float16* wlds = (_Float16*)smem;            // 98304 B: rec weights
  float* pre  = (float*)(smem + 98304);        // 768 rows x stride 17 f32 = 52224 B
  float* wred = (float*)(smem + 150528);       // 4096 B

  const int tid = threadIdx.x;
  const int l64 = tid & 63, lr = l64 & 15, lg = l64 >> 4;
  const int wv = tid >> 6, kq = wv & 3, mg = wv >> 2;
  const int blk = blockIdx.x;
  const int j16 = blk & 63, l = (blk >> 6) & 1, d = blk >> 7;
  const int idx = blk & 127;
  const int j0 = j16 * 16;

  // kill stale L1/L2 lines from previous graph replays (one buffer_inv/block)
  if (tid == 0)
    (void)__hip_atomic_load(p.flags, __ATOMIC_ACQUIRE, __HIP_MEMORY_SCOPE_AGENT);
  __syncthreads();

  const size_t tileoff = (size_t)((d * 2 + l) * 64 + j16) * 49152;
  {
    const float4* src = (const float4*)(p.wrec + tileoff);
    float4* dst = (float4*)wlds;
    #pragma unroll
    for (int i = 0; i < 12; ++i) dst[tid + i * 512] = src[tid + i * 512];
  }
  const _Float16* wtile = p.winp + tileoff;
  _Float16* hrec_arr = l ? p.h1 : p.h0;

  // ---- winp slice -> registers (96 VGPR), reused all 129 phases ----
  uint4 wreg[24];
  #pragma unroll
  for (int i = 0; i < 24; ++i) {
    const int kcl = i / 3, g = i % 3;
    const int kc = kq * 8 + kcl;
    wreg[i] = *(const uint4*)(wtile + ((size_t)(g * 32 + kc) * 64 + l64) * 8);
  }

  // ---- prologue hoists: bias / wordW / c-state live in registers ----
  const int pr = tid >> 3;          // pointwise row 0..63
  const int pj = (tid & 7) * 2;     // pointwise col pair
  const int pjg = j0 + pj;
  const float bsf0 = p.bias[d][0][l * E_SZ + pjg], bsf1 = p.bias[d][0][l * E_SZ + pjg + 1];
  const float bsi0 = p.bias[d][1][l * E_SZ + pjg], bsi1 = p.bias[d][1][l * E_SZ + pjg + 1];
  const float bsc0 = p.bias[d][2][l * E_SZ + pjg], bsc1 = p.bias[d][2][l * E_SZ + pjg + 1];
  const float ww0 = p.wordW[d * E_SZ + pjg], ww1 = p.wordW[d * E_SZ + pjg + 1];
  float creg0 = p.cs0[(size_t)pr * E_SZ + pjg];
  float creg1 = p.cs0[(size_t)pr * E_SZ + pjg + 1];
  __syncthreads();

  auto hoff = [&](int dd, int s) -> size_t {
    return (MODE == 0) ? ((size_t)dd * 129 + s) * 65536 : ((size_t)(dd * 2 + s)) * 65536;
  };

  for (int ph = 0; ph < NPHASE; ++ph) {
    const int t = l ? (ph - 1) : ph;
    if ((unsigned)t < (unsigned)S_LEN) {
      const int par = t & 1, prev = par ^ 1;
      const int td = d ? (S_LEN - 1 - t) : t;
      const int rs    = (MODE == 0) ? t : prev;       // recurrent read slot
      const int wslot = (MODE == 0) ? (t + 1) : par;  // write slot
      const int islot = (MODE == 0) ? (t + 1) : par;  // l1 input slot (h0)

      const _Float16* hAf = hrec_arr + hoff(d, rs);
      const _Float16* r0 = hAf + (size_t)(mg * 32 + lr) * 1024;
      const _Float16* r1 = hAf + (size_t)(mg * 32 + 16 + lr) * 1024;
      const _Float16* a0base;
      const _Float16* a1base;
      if (l == 0) {
        a0base = p.x16 + ((size_t)(mg * 32 + lr) * S_LEN + td) * 1024;
        a1base = p.x16 + ((size_t)(mg * 32 + 16 + lr) * S_LEN + td) * 1024;
      } else {
        const _Float16* hf = p.h0 + hoff(d, islot);
        a0base = hf + (size_t)(mg * 32 + lr) * 1024;
        a1base = hf + (size_t)(mg * 32 + 16 + lr) * 1024;
      }

      const f32x4 zero = {0.f, 0.f, 0.f, 0.f};
      f32x4 acc[3][2];
      #pragma unroll
      for (int g = 0; g < 3; ++g) { acc[g][0] = zero; acc[g][1] = zero; }

      auto issue_rec = [&](int c, uint4* Q) {
        const int kk = (kq * 8 + c * 2) * 32 + lg * 8;
        if (MODE == 0) {
          S_ISSUE_A4P(Q, r0 + kk, r1 + kk, r0 + kk + 32, r1 + kk + 32);
        } else {
          S_ISSUE_A4C(Q, r0 + kk, r1 + kk, r0 + kk + 32, r1 + kk + 32);
        }
      };
      auto issue_a = [&](int c, uint4* Q) {
        const int kk = (kq * 8 + c * 2) * 32 + lg * 8;
        if (MODE == 0 || l == 0) {
          S_ISSUE_A4P(Q, a0base + kk, a1base + kk, a0base + kk + 32, a1base + kk + 32);
        } else {
          S_ISSUE_A4C(Q, a0base + kk, a1base + kk, a0base + kk + 32, a1base + kk + 32);
        }
      };

      // ---- 3-buffer, 8-stage pipeline (s0-3 rec, s4-7 input), vmcnt(8) ----
      uint4 b0[4], b1[4], b2[4];
      issue_rec(0, b0); issue_rec(1, b1); issue_rec(2, b2);
      S_WAITV(8); comp_rec2s(b0, kq * 8 + 0, wlds, l64, acc); issue_rec(3, b0);
      S_WAITV(8); comp_rec2s(b1, kq * 8 + 2, wlds, l64, acc); issue_a(0, b1);
      S_WAITV(8); comp_rec2s(b2, kq * 8 + 4, wlds, l64, acc); issue_a(1, b2);
      S_WAITV(8); comp_rec2s(b0, kq * 8 + 6, wlds, l64, acc); issue_a(2, b0);
      S_WAITV(8); comp_inp2(b1, &wreg[0],  acc); issue_a(3, b1);
      S_WAITV(8); comp_inp2(b2, &wreg[6],  acc);
      S_WAITV(4); comp_inp2(b0, &wreg[12], acc);
      S_WAITV(0); comp_inp2(b1, &wreg[18], acc);

      // ---- reduce kq partials (stride-17: odd stride mixes bank parity) ----
      #pragma unroll
      for (int g = 0; g < 3; ++g)
        #pragma unroll
        for (int mt = 0; mt < 2; ++mt)
          #pragma unroll
          for (int pp = 0; pp < 4; ++pp)
            pre[(((kq * 3 + g) * 64) + (mg * 2 + mt) * 16 + lg * 4 + pp) * 17 + lr] =
                acc[g][mt][pp];
      __syncthreads();

      // ---- pointwise LSTM update (1 row x 2 cols per thread) ----
      float fp0 = bsf0, fp1 = bsf1, ip0 = bsi0, ip1 = bsi1, cp0 = bsc0, cp1 = bsc1;
      #pragma unroll
      for (int k = 0; k < 4; ++k) {
        fp0 += pre[((k * 3 + 0) * 64 + pr) * 17 + pj];
        fp1 += pre[((k * 3 + 0) * 64 + pr) * 17 + pj + 1];
        ip0 += pre[((k * 3 + 1) * 64 + pr) * 17 + pj];
        ip1 += pre[((k * 3 + 1) * 64 + pr) * 17 + pj + 1];
        cp0 += pre[((k * 3 + 2) * 64 + pr) * 17 + pj];
        cp1 += pre[((k * 3 + 2) * 64 + pr) * 17 + pj + 1];
      }
      const float fg0 = 1.f / (1.f + expf(-fp0)), fg1 = 1.f / (1.f + expf(-fp1));
      const float ig0 = 1.f / (1.f + expf(-ip0)), ig1 = 1.f / (1.f + expf(-ip1));
      const float gg0 = tanhf(cp0), gg1 = tanhf(cp1);
      creg0 = creg0 * fg0 + ig0 * gg0;
      creg1 = creg1 * fg1 + ig1 * gg1;
      const float h0v = tanhf(creg0) * fg0;    // forget gate reused as output gate
      const float h1v = tanhf(creg1) * fg1;

      uint32_t* hdst = (uint32_t*)(hrec_arr + hoff(d, wslot) + (size_t)pr * 1024 + pjg);
      const uint32_t pk = pack2f16(h0v, h1v);
      asm volatile("global_store_dword %0, %1, off sc0 sc1" ::"v"(hdst), "v"(pk) : "memory");
      if (l) {
        wred[pr * 16 + pj] = h0v * ww0;
        wred[pr * 16 + pj + 1] = h1v * ww1;
        __syncthreads();
        if (tid < 64) {
          float s = 0.f;
          #pragma unroll
          for (int q = 0; q < 16; ++q) s += wred[tid * 16 + q];
          p.wpart[((size_t)(d * 64 + j16) * S_LEN + td) * 64 + tid] = s;
        }
      }
    }

    // ---- flat 1-hop barrier: own flag store + parallel poll of all 128 ----
    __syncthreads();   // drains each wave's vmcnt -> h stores at coherence point
    if (tid == 0) {
      __hip_atomic_store(p.flags + (size_t)(d * 128 + idx) * 32, ph + 1,
                         __ATOMIC_RELAXED, __HIP_MEMORY_SCOPE_AGENT);
      asm volatile("s_waitcnt vmcnt(0)" ::: "memory");
    }
    if (tid < 128) {
      const int* fl = p.flags + (size_t)(d * 128 + tid) * 32;
      int f, it = 0;
      do {
        f = __hip_atomic_load(fl, __ATOMIC_RELAXED, __HIP_MEMORY_SCOPE_AGENT);
        if (f >= ph + 1) break;
        __builtin_amdgcn_s_sleep(1);
      } while (++it < (1 << 22));
    }
    __syncthreads();
  }
}

// w[b][t] = word_b + sum over (d,j16) of wpart
__global__ __launch_bounds__(64)
void reduce_w_kernel(const float* wpart, const float* wordb, float* w) {
  const int t = blockIdx.x, b = threadIdx.x;
  float s = wordb[0];
  #pragma unroll 8
  for (int q = 0; q < 128; ++q)
    s += wpart[((size_t)q * S_LEN + t) * 64 + b];
  w[b * S_LEN + t] = s;
}

__global__ __launch_bounds__(320)
void final_kernel(const float* w, const float* predW, const float* predb, float* out) {
  const int tid = threadIdx.x;
  if (tid >= B_SZ * NLBL) return;
  const int b = tid / NLBL, lab = tid % NLBL;
  float s = predb[lab];
  #pragma unroll 8
  for (int t = 0; t < S_LEN; ++t) s += w[b * S_LEN + t] * predW[t * NLBL + lab];
  out[tid] = s;
}

// ================= launcher =================
extern "C" void kernel_launch(void* const* d_in, const int* in_sizes, int n_in,
                              void* d_out, int out_size, void* d_ws, size_t ws_size,
                              hipStream_t stream) {
  char* ws = (char*)d_ws;
  const bool hist = (ws_size >= NEED0);

  PP p;
  p.x = (const float*)d_in[0];
  p.W[0][0] = (const float*)d_in[5];  p.bias[0][0] = (const float*)d_in[6];
  p.W[0][1] = (const float*)d_in[7];  p.bias[0][1] = (const float*)d_in[8];
  p.W[0][2] = (const float*)d_in[9];  p.bias[0][2] = (const float*)d_in[10];
  p.W[1][0] = (const float*)d_in[11]; p.bias[1][0] = (const float*)d_in[12];
  p.W[1][1] = (const float*)d_in[13]; p.bias[1][1] = (const float*)d_in[14];
  p.W[1][2] = (const float*)d_in[15]; p.bias[1][2] = (const float*)d_in[16];
  p.wordW = (const float*)d_in[17];
  p.cs0   = (const float*)d_in[1];
  p.wrec  = (_Float16*)(ws + WOFF_WREC);
  p.winp  = (_Float16*)(ws + WOFF_WINP);
  p.x16   = (_Float16*)(ws + WOFF_X16);
  if (hist) {
    p.h0    = (_Float16*)(ws + M0_H0);
    p.h1    = (_Float16*)(ws + M0_H1);
    p.wpart = (float*)(ws + M0_WPART);
    p.w     = (float*)(ws + M0_W);
    p.flags = (int*)(ws + M0_FLAGS);
  } else {
    p.h0    = (_Float16*)(ws + M1_H0);
    p.h1    = (_Float16*)(ws + M1_H1);
    p.wpart = (float*)(ws + M1_WPART);
    p.w     = (float*)(ws + M1_W);
    p.flags = (int*)(ws + M1_FLAGS);
  }

  hipFuncSetAttribute(reinterpret_cast<const void*>(&lstm_persist<0>),
                      hipFuncAttributeMaxDynamicSharedMemorySize, 155648);
  hipFuncSetAttribute(reinterpret_cast<const void*>(&lstm_persist<1>),
                      hipFuncAttributeMaxDynamicSharedMemorySize, 155648);

  conv_w_kernel<<<1536, 256, 0, stream>>>(p);
  conv_x_kernel<<<4096, 256, 0, stream>>>(p.x, p.x16);
  if (hist) {
    init2_kernel<0><<<544, 256, 0, stream>>>(p, (const float*)d_in[2]);
    lstm_persist<0><<<256, 512, 155648, stream>>>(p);
  } else {
    init2_kernel<1><<<1056, 256, 0, stream>>>(p, (const float*)d_in[2]);
    lstm_persist<1><<<256, 512, 155648, stream>>>(p);
  }
  reduce_w_kernel<<<128, 64, 0, stream>>>(p.wpart, (const float*)d_in[18], p.w);
  final_kernel<<<1, 320, 0, stream>>>(p.w, (const float*)d_in[19],
                                      (const float*)d_in[20], (float*)d_out);
}